// Round 1
// baseline (30069.913 us; speedup 1.0000x reference)
//
#include <hip/hip_runtime.h>
#include <math.h>

#define S_LEN 2048
#define DMODEL 768
#define NHEAD 12
#define DHEAD 64
#define NLAYER 12
#define FFDIM 3072
#define CHUNK 128
#define NCHUNK 16

__device__ __forceinline__ float gelu_f(float x) {
  return 0.5f * x * (1.0f + erff(x * 0.7071067811865476f));
}

// ---------------- embedding + LN ----------------
__global__ __launch_bounds__(256) void embed_ln_kernel(
    const int* __restrict__ ids, const float* __restrict__ wemb,
    const float* __restrict__ pemb, const float* __restrict__ g,
    const float* __restrict__ b, float* __restrict__ x)
{
  const int s = blockIdx.x, tid = threadIdx.x;
  __shared__ float red[4];
  const size_t wbase = (size_t)ids[s] * DMODEL;
  const size_t pbase = (size_t)s * DMODEL;
  float y0 = wemb[wbase + tid]       + pemb[pbase + tid];
  float y1 = wemb[wbase + tid + 256] + pemb[pbase + tid + 256];
  float y2 = wemb[wbase + tid + 512] + pemb[pbase + tid + 512];
  float sum = y0 + y1 + y2;
  #pragma unroll
  for (int off = 32; off; off >>= 1) sum += __shfl_down(sum, off);
  if ((tid & 63) == 0) red[tid >> 6] = sum;
  __syncthreads();
  const float mean = (red[0] + red[1] + red[2] + red[3]) * (1.0f / 768.0f);
  __syncthreads();
  float d0 = y0 - mean, d1 = y1 - mean, d2 = y2 - mean;
  float vs = d0*d0 + d1*d1 + d2*d2;
  #pragma unroll
  for (int off = 32; off; off >>= 1) vs += __shfl_down(vs, off);
  if ((tid & 63) == 0) red[tid >> 6] = vs;
  __syncthreads();
  const float rstd = rsqrtf((red[0]+red[1]+red[2]+red[3]) * (1.0f/768.0f) + 1e-5f);
  x[pbase + tid]       = d0 * rstd * g[tid]       + b[tid];
  x[pbase + tid + 256] = d1 * rstd * g[tid + 256] + b[tid + 256];
  x[pbase + tid + 512] = d2 * rstd * g[tid + 512] + b[tid + 512];
}

// ---------------- residual add + LN (in-place on x) ----------------
__global__ __launch_bounds__(256) void add_ln_kernel(
    float* __restrict__ x, const float* __restrict__ t,
    const float* __restrict__ g, const float* __restrict__ b)
{
  const int s = blockIdx.x, tid = threadIdx.x;
  __shared__ float red[4];
  const size_t base = (size_t)s * DMODEL;
  float y0 = x[base + tid]       + t[base + tid];
  float y1 = x[base + tid + 256] + t[base + tid + 256];
  float y2 = x[base + tid + 512] + t[base + tid + 512];
  float sum = y0 + y1 + y2;
  #pragma unroll
  for (int off = 32; off; off >>= 1) sum += __shfl_down(sum, off);
  if ((tid & 63) == 0) red[tid >> 6] = sum;
  __syncthreads();
  const float mean = (red[0] + red[1] + red[2] + red[3]) * (1.0f / 768.0f);
  __syncthreads();
  float d0 = y0 - mean, d1 = y1 - mean, d2 = y2 - mean;
  float vs = d0*d0 + d1*d1 + d2*d2;
  #pragma unroll
  for (int off = 32; off; off >>= 1) vs += __shfl_down(vs, off);
  if ((tid & 63) == 0) red[tid >> 6] = vs;
  __syncthreads();
  const float rstd = rsqrtf((red[0]+red[1]+red[2]+red[3]) * (1.0f/768.0f) + 1e-5f);
  x[base + tid]       = d0 * rstd * g[tid]       + b[tid];
  x[base + tid + 256] = d1 * rstd * g[tid + 256] + b[tid + 256];
  x[base + tid + 512] = d2 * rstd * g[tid + 512] + b[tid + 512];
}

// ---------------- LN of a single 768-vector ----------------
__global__ __launch_bounds__(256) void ln_vec_kernel(
    const float* __restrict__ in, const float* __restrict__ g,
    const float* __restrict__ b, float* __restrict__ out)
{
  const int tid = threadIdx.x;
  __shared__ float red[4];
  float y0 = in[tid], y1 = in[tid + 256], y2 = in[tid + 512];
  float sum = y0 + y1 + y2;
  #pragma unroll
  for (int off = 32; off; off >>= 1) sum += __shfl_down(sum, off);
  if ((tid & 63) == 0) red[tid >> 6] = sum;
  __syncthreads();
  const float mean = (red[0] + red[1] + red[2] + red[3]) * (1.0f / 768.0f);
  __syncthreads();
  float d0 = y0 - mean, d1 = y1 - mean, d2 = y2 - mean;
  float vs = d0*d0 + d1*d1 + d2*d2;
  #pragma unroll
  for (int off = 32; off; off >>= 1) vs += __shfl_down(vs, off);
  if ((tid & 63) == 0) red[tid >> 6] = vs;
  __syncthreads();
  const float rstd = rsqrtf((red[0]+red[1]+red[2]+red[3]) * (1.0f/768.0f) + 1e-5f);
  out[tid]       = d0 * rstd * g[tid]       + b[tid];
  out[tid + 256] = d1 * rstd * g[tid + 256] + b[tid + 256];
  out[tid + 512] = d2 * rstd * g[tid + 512] + b[tid + 512];
}

// ---------------- generic tiled f32 GEMM: C = act(A @ W + bias) ----------------
// A [M,K] rm, W [K,N] rm, C [M,N] rm. M%64==0, N%64==0, K%16==0.
__global__ __launch_bounds__(256) void gemm_bias_act_kernel(
    const float* __restrict__ A, const float* __restrict__ W,
    const float* __restrict__ bias, float* __restrict__ C,
    int M, int N, int K, int act)
{
  __shared__ float As[16][64];
  __shared__ float Bs[16][64];
  const int bm = blockIdx.x * 64, bn = blockIdx.y * 64;
  const int tid = threadIdx.x;
  const int tx = tid & 15, ty = tid >> 4;
  float acc[4][4] = {};
  for (int k0 = 0; k0 < K; k0 += 16) {
    #pragma unroll
    for (int e = tid; e < 64 * 16; e += 256) {
      const int m = e >> 4, kk = e & 15;
      As[kk][m] = A[(size_t)(bm + m) * K + k0 + kk];
    }
    #pragma unroll
    for (int e = tid; e < 16 * 64; e += 256) {
      const int kk = e >> 6, n = e & 63;
      Bs[kk][n] = W[(size_t)(k0 + kk) * N + bn + n];
    }
    __syncthreads();
    #pragma unroll
    for (int kk = 0; kk < 16; ++kk) {
      float a[4], bb[4];
      #pragma unroll
      for (int i = 0; i < 4; ++i) a[i] = As[kk][ty + 16 * i];
      #pragma unroll
      for (int j = 0; j < 4; ++j) bb[j] = Bs[kk][tx + 16 * j];
      #pragma unroll
      for (int i = 0; i < 4; ++i)
        #pragma unroll
        for (int j = 0; j < 4; ++j)
          acc[i][j] = fmaf(a[i], bb[j], acc[i][j]);
    }
    __syncthreads();
  }
  #pragma unroll
  for (int i = 0; i < 4; ++i) {
    const int m = bm + ty + 16 * i;
    #pragma unroll
    for (int j = 0; j < 4; ++j) {
      const int n = bn + tx + 16 * j;
      float o = acc[i][j] + bias[n];
      if (act == 1) o = gelu_f(o);
      C[(size_t)m * N + n] = o;
    }
  }
}

// ---------------- GEMV (row vector @ W + bias), optional GELU ----------------
__global__ __launch_bounds__(256) void gemv_kernel(
    const float* __restrict__ xrow, const float* __restrict__ W,
    const float* __restrict__ bias, float* __restrict__ y,
    int N, int K, int act)
{
  const int n = blockIdx.x * 256 + threadIdx.x;
  if (n >= N) return;
  float s = 0.f;
  for (int kk = 0; kk < K; ++kk) s = fmaf(xrow[kk], W[(size_t)kk * N + n], s);
  s += bias[n];
  if (act) s = gelu_f(s);
  y[n] = s;
}

// ---------------- banded (sliding-window) attention, one block per (head, chunk) ----------------
// thread r handles query row s = nc*128 + r. Online softmax over [CLS key | 384 banded keys].
__global__ __launch_bounds__(128) void banded_attn_kernel(
    const float* __restrict__ q, const float* __restrict__ k,
    const float* __restrict__ v, const int* __restrict__ am,
    float* __restrict__ outb)
{
  const int h = blockIdx.x;
  const int nc = blockIdx.y;
  const int r = threadIdx.x;
  const int s = nc * CHUNK + r;

  float qr[64];
  #pragma unroll
  for (int d0 = 0; d0 < 64; d0 += 4) {
    const float4 t4 = *reinterpret_cast<const float4*>(&q[(size_t)s * DMODEL + h * DHEAD + d0]);
    qr[d0] = t4.x * 0.125f; qr[d0+1] = t4.y * 0.125f; qr[d0+2] = t4.z * 0.125f; qr[d0+3] = t4.w * 0.125f;
  }
  float m = -1e30f, l = 0.f;
  float acc[64];
  #pragma unroll
  for (int d = 0; d < 64; ++d) acc[d] = 0.f;

  // global CLS key (k row 0), attended by every query; masked only by am[0]
  if (am[0] > 0) {
    float sc = 0.f;
    #pragma unroll
    for (int d0 = 0; d0 < 64; d0 += 4) {
      const float4 k4 = *reinterpret_cast<const float4*>(&k[h * DHEAD + d0]);
      sc = fmaf(qr[d0], k4.x, fmaf(qr[d0+1], k4.y, fmaf(qr[d0+2], k4.z, fmaf(qr[d0+3], k4.w, sc))));
    }
    const float newm = fmaxf(m, sc);
    const float corr = expf(m - newm);
    const float p = expf(sc - newm);
    l = l * corr + p;
    #pragma unroll
    for (int d0 = 0; d0 < 64; d0 += 4) {
      const float4 v4 = *reinterpret_cast<const float4*>(&v[h * DHEAD + d0]);
      acc[d0]   = fmaf(acc[d0],   corr, p * v4.x);
      acc[d0+1] = fmaf(acc[d0+1], corr, p * v4.y);
      acc[d0+2] = fmaf(acc[d0+2], corr, p * v4.z);
      acc[d0+3] = fmaf(acc[d0+3], corr, p * v4.w);
    }
    m = newm;
  }

  const int kbase = nc * CHUNK - CHUNK;
  for (int j = 0; j < 3 * CHUNK; ++j) {
    const int kj = kbase + j;            // uniform across the wave
    if (kj < 1 || kj >= S_LEN) continue; // uniform branch
    const int diff = r + CHUNK - j;      // qi - kj
    const bool ok = (diff >= -128) && (diff <= 128) && (am[kj] > 0);
    float sc = 0.f;
    #pragma unroll
    for (int d0 = 0; d0 < 64; d0 += 4) {
      const float4 k4 = *reinterpret_cast<const float4*>(&k[(size_t)kj * DMODEL + h * DHEAD + d0]);
      sc = fmaf(qr[d0], k4.x, fmaf(qr[d0+1], k4.y, fmaf(qr[d0+2], k4.z, fmaf(qr[d0+3], k4.w, sc))));
    }
    if (!ok) continue;
    const float newm = fmaxf(m, sc);
    const float corr = expf(m - newm);
    const float p = expf(sc - newm);
    l = l * corr + p;
    #pragma unroll
    for (int d0 = 0; d0 < 64; d0 += 4) {
      const float4 v4 = *reinterpret_cast<const float4*>(&v[(size_t)kj * DMODEL + h * DHEAD + d0]);
      acc[d0]   = fmaf(acc[d0],   corr, p * v4.x);
      acc[d0+1] = fmaf(acc[d0+1], corr, p * v4.y);
      acc[d0+2] = fmaf(acc[d0+2], corr, p * v4.z);
      acc[d0+3] = fmaf(acc[d0+3], corr, p * v4.w);
    }
    m = newm;
  }

  const float rl = (l > 0.f) ? 1.f / l : 0.f;
  #pragma unroll
  for (int d = 0; d < 64; ++d)
    outb[(size_t)s * DMODEL + h * DHEAD + d] = acc[d] * rl;
}

// ---------------- global (CLS) query row: attends all tokens with global projections ----------------
__global__ __launch_bounds__(256) void global_attn_kernel(
    const float* __restrict__ qg0, const float* __restrict__ kg,
    const float* __restrict__ vg, const int* __restrict__ am,
    float* __restrict__ outb)
{
  const int h = blockIdx.x, tid = threadIdx.x;
  __shared__ float sc[S_LEN];
  __shared__ float qs[DHEAD];
  __shared__ float red[4];
  __shared__ float pbuf[4][DHEAD];
  if (tid < DHEAD) qs[tid] = qg0[h * DHEAD + tid] * 0.125f;
  __syncthreads();
  for (int s0 = tid; s0 < S_LEN; s0 += 256) {
    float d = 0.f;
    const float* kr = &kg[(size_t)s0 * DMODEL + h * DHEAD];
    #pragma unroll
    for (int d0 = 0; d0 < DHEAD; d0 += 4)
      d += qs[d0]*kr[d0] + qs[d0+1]*kr[d0+1] + qs[d0+2]*kr[d0+2] + qs[d0+3]*kr[d0+3];
    sc[s0] = (am[s0] > 0) ? d : -1e9f;
  }
  __syncthreads();
  float mx = -1e30f;
  for (int s0 = tid; s0 < S_LEN; s0 += 256) mx = fmaxf(mx, sc[s0]);
  #pragma unroll
  for (int off = 32; off; off >>= 1) mx = fmaxf(mx, __shfl_down(mx, off));
  if ((tid & 63) == 0) red[tid >> 6] = mx;
  __syncthreads();
  mx = fmaxf(fmaxf(red[0], red[1]), fmaxf(red[2], red[3]));
  __syncthreads();
  float sum = 0.f;
  for (int s0 = tid; s0 < S_LEN; s0 += 256) { const float e = expf(sc[s0] - mx); sc[s0] = e; sum += e; }
  #pragma unroll
  for (int off = 32; off; off >>= 1) sum += __shfl_down(sum, off);
  if ((tid & 63) == 0) red[tid >> 6] = sum;
  __syncthreads();
  const float total = red[0] + red[1] + red[2] + red[3];
  const int d = tid & 63, grp = tid >> 6;
  float part = 0.f;
  for (int s0 = grp; s0 < S_LEN; s0 += 4)
    part = fmaf(sc[s0], vg[(size_t)s0 * DMODEL + h * DHEAD + d], part);
  pbuf[grp][d] = part;
  __syncthreads();
  if (tid < DHEAD) {
    const float o = (pbuf[0][tid] + pbuf[1][tid] + pbuf[2][tid] + pbuf[3][tid]) / total;
    outb[h * DHEAD + tid] = o;  // row 0 of attn output
  }
}

// ---------------- final head: logit = h2 . Wout + bout; out = sigmoid ----------------
// Hedged write: f32 value whose low 16 bits are the RNE bf16 encoding of the same value.
__global__ __launch_bounds__(256) void head_final_kernel(
    const float* __restrict__ h2, const float* __restrict__ Wout,
    const float* __restrict__ bout, float* __restrict__ out)
{
  const int tid = threadIdx.x;
  __shared__ float red[4];
  float p = h2[tid]*Wout[tid] + h2[tid+256]*Wout[tid+256] + h2[tid+512]*Wout[tid+512];
  #pragma unroll
  for (int off = 32; off; off >>= 1) p += __shfl_down(p, off);
  if ((tid & 63) == 0) red[tid >> 6] = p;
  __syncthreads();
  if (tid == 0) {
    const float logit = red[0] + red[1] + red[2] + red[3] + bout[0];
    const float sig = 1.0f / (1.0f + expf(-logit));
    const unsigned int bits = __float_as_uint(sig);
    const unsigned int bf = (bits + 0x7FFFu + ((bits >> 16) & 1u)) >> 16; // RNE bf16
    const unsigned int hedged = (bits & 0xFFFF0000u) | (bf & 0xFFFFu);
    out[0] = __uint_as_float(hedged);
  }
}

extern "C" void kernel_launch(void* const* d_in, const int* in_sizes, int n_in,
                              void* d_out, int out_size, void* d_ws, size_t ws_size,
                              hipStream_t stream)
{
  const int*   ids  = (const int*)d_in[0];
  const int*   am   = (const int*)d_in[1];
  const float* wemb = (const float*)d_in[2];
  const float* pemb = (const float*)d_in[3];
  const float* emb_g = (const float*)d_in[4];
  const float* emb_b = (const float*)d_in[5];
  const float* Wq  = (const float*)d_in[6];
  const float* bq  = (const float*)d_in[7];
  const float* Wk  = (const float*)d_in[8];
  const float* bk  = (const float*)d_in[9];
  const float* Wv  = (const float*)d_in[10];
  const float* bv  = (const float*)d_in[11];
  const float* Wqg = (const float*)d_in[12];
  const float* bqg = (const float*)d_in[13];
  const float* Wkg = (const float*)d_in[14];
  const float* bkg = (const float*)d_in[15];
  const float* Wvg = (const float*)d_in[16];
  const float* bvg = (const float*)d_in[17];
  const float* Wo  = (const float*)d_in[18];
  const float* bo  = (const float*)d_in[19];
  const float* ln1g = (const float*)d_in[20];
  const float* ln1b = (const float*)d_in[21];
  const float* Wf1 = (const float*)d_in[22];
  const float* bf1 = (const float*)d_in[23];
  const float* Wf2 = (const float*)d_in[24];
  const float* bf2 = (const float*)d_in[25];
  const float* ln2g = (const float*)d_in[26];
  const float* ln2b = (const float*)d_in[27];
  const float* hng = (const float*)d_in[28];
  const float* hnb = (const float*)d_in[29];
  const float* W1  = (const float*)d_in[30];
  const float* b1  = (const float*)d_in[31];
  const float* W2  = (const float*)d_in[32];
  const float* b2  = (const float*)d_in[33];
  const float* Wout = (const float*)d_in[34];
  const float* bout = (const float*)d_in[35];

  float* ws = (float*)d_ws;
  const size_t SD = (size_t)S_LEN * DMODEL;
  float* x     = ws;
  float* q     = x + SD;
  float* k     = q + SD;
  float* v     = k + SD;
  float* kgb   = v + SD;
  float* vgb   = kgb + SD;
  float* attnb = vgb + SD;
  float* tmp   = attnb + SD;                     // S_LEN * FFDIM
  float* qg0   = tmp + (size_t)S_LEN * FFDIM;
  float* hb    = qg0 + DMODEL;                   // 3 * DMODEL

  embed_ln_kernel<<<S_LEN, 256, 0, stream>>>(ids, wemb, pemb, emb_g, emb_b, x);

  const dim3 gdd(S_LEN / 64, DMODEL / 64);
  const dim3 gdf(S_LEN / 64, FFDIM / 64);

  for (int l = 0; l < NLAYER; ++l) {
    const size_t wdd = (size_t)l * DMODEL * DMODEL;
    const size_t wdf = (size_t)l * DMODEL * FFDIM;
    const size_t vd  = (size_t)l * DMODEL;
    const size_t vf  = (size_t)l * FFDIM;

    gemm_bias_act_kernel<<<gdd, 256, 0, stream>>>(x, Wq + wdd, bq + vd, q, S_LEN, DMODEL, DMODEL, 0);
    gemm_bias_act_kernel<<<gdd, 256, 0, stream>>>(x, Wk + wdd, bk + vd, k, S_LEN, DMODEL, DMODEL, 0);
    gemm_bias_act_kernel<<<gdd, 256, 0, stream>>>(x, Wv + wdd, bv + vd, v, S_LEN, DMODEL, DMODEL, 0);
    gemm_bias_act_kernel<<<gdd, 256, 0, stream>>>(x, Wkg + wdd, bkg + vd, kgb, S_LEN, DMODEL, DMODEL, 0);
    gemm_bias_act_kernel<<<gdd, 256, 0, stream>>>(x, Wvg + wdd, bvg + vd, vgb, S_LEN, DMODEL, DMODEL, 0);
    gemv_kernel<<<3, 256, 0, stream>>>(x, Wqg + wdd, bqg + vd, qg0, DMODEL, DMODEL, 0);

    banded_attn_kernel<<<dim3(NHEAD, NCHUNK), 128, 0, stream>>>(q, k, v, am, attnb);
    global_attn_kernel<<<NHEAD, 256, 0, stream>>>(qg0, kgb, vgb, am, attnb);

    gemm_bias_act_kernel<<<gdd, 256, 0, stream>>>(attnb, Wo + wdd, bo + vd, tmp, S_LEN, DMODEL, DMODEL, 0);
    add_ln_kernel<<<S_LEN, 256, 0, stream>>>(x, tmp, ln1g + vd, ln1b + vd);

    gemm_bias_act_kernel<<<gdf, 256, 0, stream>>>(x, Wf1 + wdf, bf1 + vf, tmp, S_LEN, FFDIM, DMODEL, 1);
    gemm_bias_act_kernel<<<gdd, 256, 0, stream>>>(tmp, Wf2 + wdf, bf2 + vd, attnb, S_LEN, DMODEL, FFDIM, 0);
    add_ln_kernel<<<S_LEN, 256, 0, stream>>>(x, attnb, ln2g + vd, ln2b + vd);
  }

  ln_vec_kernel<<<1, 256, 0, stream>>>(x, hng, hnb, hb);
  gemv_kernel<<<3, 256, 0, stream>>>(hb, W1, b1, hb + DMODEL, DMODEL, DMODEL, 1);
  gemv_kernel<<<3, 256, 0, stream>>>(hb + DMODEL, W2, b2, hb + 2 * DMODEL, DMODEL, DMODEL, 1);
  head_final_kernel<<<1, 256, 0, stream>>>(hb + 2 * DMODEL, Wout, bout, (float*)d_out);
}

// Round 2
// 7067.865 us; speedup vs baseline: 4.2545x; 4.2545x over previous
//
#include <hip/hip_runtime.h>
#include <math.h>

#define S_LEN 2048
#define DMODEL 768
#define NHEAD 12
#define DHEAD 64
#define NLAYER 12
#define FFDIM 3072
#define CHUNK 128
#define NCHUNK 16
#define QKV_N 3840   // q|k|v|kg|vg concatenated

typedef __attribute__((ext_vector_type(8))) short short8;
typedef __attribute__((ext_vector_type(4))) float f32x4;

__device__ __forceinline__ float gelu_f(float x) {
  return 0.5f * x * (1.0f + erff(x * 0.7071067811865476f));
}
// float -> bf16 bits (RNE)
__device__ __forceinline__ unsigned short f2b(float f) {
  unsigned int u = __float_as_uint(f);
  return (unsigned short)((u + 0x7FFFu + ((u >> 16) & 1u)) >> 16);
}

// ================= LayerNorm family (f32 math, optional bf16 copy) =================
__global__ __launch_bounds__(256) void embed_ln_kernel(
    const int* __restrict__ ids, const float* __restrict__ wemb,
    const float* __restrict__ pemb, const float* __restrict__ g,
    const float* __restrict__ b, float* __restrict__ x, unsigned short* __restrict__ xb)
{
  const int s = blockIdx.x, tid = threadIdx.x;
  __shared__ float red[4];
  const size_t wbase = (size_t)ids[s] * DMODEL;
  const size_t pbase = (size_t)s * DMODEL;
  float y0 = wemb[wbase + tid]       + pemb[pbase + tid];
  float y1 = wemb[wbase + tid + 256] + pemb[pbase + tid + 256];
  float y2 = wemb[wbase + tid + 512] + pemb[pbase + tid + 512];
  float sum = y0 + y1 + y2;
  #pragma unroll
  for (int off = 32; off; off >>= 1) sum += __shfl_down(sum, off);
  if ((tid & 63) == 0) red[tid >> 6] = sum;
  __syncthreads();
  const float mean = (red[0] + red[1] + red[2] + red[3]) * (1.0f / 768.0f);
  __syncthreads();
  float d0 = y0 - mean, d1 = y1 - mean, d2 = y2 - mean;
  float vs = d0*d0 + d1*d1 + d2*d2;
  #pragma unroll
  for (int off = 32; off; off >>= 1) vs += __shfl_down(vs, off);
  if ((tid & 63) == 0) red[tid >> 6] = vs;
  __syncthreads();
  const float rstd = rsqrtf((red[0]+red[1]+red[2]+red[3]) * (1.0f/768.0f) + 1e-5f);
  float o0 = d0 * rstd * g[tid]       + b[tid];
  float o1 = d1 * rstd * g[tid + 256] + b[tid + 256];
  float o2 = d2 * rstd * g[tid + 512] + b[tid + 512];
  x[pbase + tid] = o0; x[pbase + tid + 256] = o1; x[pbase + tid + 512] = o2;
  xb[pbase + tid] = f2b(o0); xb[pbase + tid + 256] = f2b(o1); xb[pbase + tid + 512] = f2b(o2);
}

__global__ __launch_bounds__(256) void add_ln_kernel(
    float* __restrict__ x, const float* __restrict__ t,
    const float* __restrict__ g, const float* __restrict__ b,
    unsigned short* __restrict__ xb)
{
  const int s = blockIdx.x, tid = threadIdx.x;
  __shared__ float red[4];
  const size_t base = (size_t)s * DMODEL;
  float y0 = x[base + tid]       + t[base + tid];
  float y1 = x[base + tid + 256] + t[base + tid + 256];
  float y2 = x[base + tid + 512] + t[base + tid + 512];
  float sum = y0 + y1 + y2;
  #pragma unroll
  for (int off = 32; off; off >>= 1) sum += __shfl_down(sum, off);
  if ((tid & 63) == 0) red[tid >> 6] = sum;
  __syncthreads();
  const float mean = (red[0] + red[1] + red[2] + red[3]) * (1.0f / 768.0f);
  __syncthreads();
  float d0 = y0 - mean, d1 = y1 - mean, d2 = y2 - mean;
  float vs = d0*d0 + d1*d1 + d2*d2;
  #pragma unroll
  for (int off = 32; off; off >>= 1) vs += __shfl_down(vs, off);
  if ((tid & 63) == 0) red[tid >> 6] = vs;
  __syncthreads();
  const float rstd = rsqrtf((red[0]+red[1]+red[2]+red[3]) * (1.0f/768.0f) + 1e-5f);
  float o0 = d0 * rstd * g[tid]       + b[tid];
  float o1 = d1 * rstd * g[tid + 256] + b[tid + 256];
  float o2 = d2 * rstd * g[tid + 512] + b[tid + 512];
  x[base + tid] = o0; x[base + tid + 256] = o1; x[base + tid + 512] = o2;
  xb[base + tid] = f2b(o0); xb[base + tid + 256] = f2b(o1); xb[base + tid + 512] = f2b(o2);
}

__global__ __launch_bounds__(256) void ln_vec_kernel(
    const float* __restrict__ in, const float* __restrict__ g,
    const float* __restrict__ b, float* __restrict__ out)
{
  const int tid = threadIdx.x;
  __shared__ float red[4];
  float y0 = in[tid], y1 = in[tid + 256], y2 = in[tid + 512];
  float sum = y0 + y1 + y2;
  #pragma unroll
  for (int off = 32; off; off >>= 1) sum += __shfl_down(sum, off);
  if ((tid & 63) == 0) red[tid >> 6] = sum;
  __syncthreads();
  const float mean = (red[0] + red[1] + red[2] + red[3]) * (1.0f / 768.0f);
  __syncthreads();
  float d0 = y0 - mean, d1 = y1 - mean, d2 = y2 - mean;
  float vs = d0*d0 + d1*d1 + d2*d2;
  #pragma unroll
  for (int off = 32; off; off >>= 1) vs += __shfl_down(vs, off);
  if ((tid & 63) == 0) red[tid >> 6] = vs;
  __syncthreads();
  const float rstd = rsqrtf((red[0]+red[1]+red[2]+red[3]) * (1.0f/768.0f) + 1e-5f);
  out[tid]       = d0 * rstd * g[tid]       + b[tid];
  out[tid + 256] = d1 * rstd * g[tid + 256] + b[tid + 256];
  out[tid + 512] = d2 * rstd * g[tid + 512] + b[tid + 512];
}

// ================= weight convert + transpose (f32 [K][N] -> bf16 [N][K]) =================
// z<5: Wq..Wvg into WqkvT (concat rows); z==5: Wo into WoT. Also concatenates biases.
__global__ __launch_bounds__(256) void conv6_kernel(
    const float* __restrict__ W0, const float* __restrict__ W1, const float* __restrict__ W2,
    const float* __restrict__ W3, const float* __restrict__ W4, const float* __restrict__ W5,
    const float* __restrict__ b0, const float* __restrict__ b1, const float* __restrict__ b2,
    const float* __restrict__ b3, const float* __restrict__ b4,
    unsigned short* __restrict__ WqkvT, unsigned short* __restrict__ WoT,
    float* __restrict__ bqkv)
{
  const int z = blockIdx.z;
  const float* src = z==0?W0: z==1?W1: z==2?W2: z==3?W3: z==4?W4: W5;
  unsigned short* dst = (z < 5) ? (WqkvT + (size_t)z * DMODEL * DMODEL) : WoT;
  __shared__ float tbuf[32][33];
  const int n0 = blockIdx.x * 32, k0 = blockIdx.y * 32;
  const int tx = threadIdx.x, ty = threadIdx.y;  // block (32,8)
  #pragma unroll
  for (int r = ty; r < 32; r += 8)
    tbuf[r][tx] = src[(size_t)(k0 + r) * DMODEL + n0 + tx];
  __syncthreads();
  #pragma unroll
  for (int r = ty; r < 32; r += 8)
    dst[(size_t)(n0 + r) * DMODEL + k0 + tx] = f2b(tbuf[tx][r]);
  if (z < 5 && blockIdx.x == 0 && blockIdx.y == 0) {
    const float* bsrc = z==0?b0: z==1?b1: z==2?b2: z==3?b3: b4;
    const int t = ty * 32 + tx;
    for (int i = t; i < DMODEL; i += 256) bqkv[z * DMODEL + i] = bsrc[i];
  }
}

// z==0: Wf1 [768][3072] -> Wf1T [3072][768]; z==1: Wf2 [3072][768] -> Wf2T [768][3072]
__global__ __launch_bounds__(256) void conv_ffn_kernel(
    const float* __restrict__ Wf1, const float* __restrict__ Wf2,
    unsigned short* __restrict__ Wf1T, unsigned short* __restrict__ Wf2T)
{
  const int z = blockIdx.z;
  __shared__ float tbuf[32][33];
  const float* src; unsigned short* dst; int Kd, Nd, n0, k0;
  if (z == 0) { src = Wf1; dst = Wf1T; Kd = DMODEL; Nd = FFDIM;
                n0 = blockIdx.x * 32; k0 = blockIdx.y * 32; }
  else        { src = Wf2; dst = Wf2T; Kd = FFDIM; Nd = DMODEL;
                n0 = blockIdx.y * 32; k0 = blockIdx.x * 32; }
  const int tx = threadIdx.x, ty = threadIdx.y;
  #pragma unroll
  for (int r = ty; r < 32; r += 8)
    tbuf[r][tx] = src[(size_t)(k0 + r) * Nd + n0 + tx];
  __syncthreads();
  #pragma unroll
  for (int r = ty; r < 32; r += 8)
    dst[(size_t)(n0 + r) * Kd + k0 + tx] = f2b(tbuf[tx][r]);
}

// ================= bf16 MFMA GEMM =================
// C[M=2048][N] = act(A[M][K]bf16 @ Bt[N][K]bf16^T + bias). 128x128 tile, BK=64,
// global_load_lds(16B) into XOR-swizzled LDS slots; 16x16x32 bf16 MFMA, 4 waves x (64x64).
__global__ __launch_bounds__(256) void gemm_mfma_kernel(
    const unsigned short* __restrict__ A, const unsigned short* __restrict__ Bt,
    const float* __restrict__ bias, float* __restrict__ Cf,
    unsigned short* __restrict__ Cb, int N, int K, int act)
{
  __shared__ unsigned short As[8192];  // 1024 slots x 16B
  __shared__ unsigned short Bs[8192];
  const int tid = threadIdx.x, wave = tid >> 6, lane = tid & 63;
  const int bm = blockIdx.x * 128, bn = blockIdx.y * 128;
  const int wr = (wave >> 1) * 64, wc = (wave & 1) * 64;
  f32x4 acc[4][4];
  const f32x4 zz = {0.f, 0.f, 0.f, 0.f};
  #pragma unroll
  for (int i = 0; i < 4; ++i)
    #pragma unroll
    for (int j = 0; j < 4; ++j) acc[i][j] = zz;

  for (int k0 = 0; k0 < K; k0 += 64) {
    #pragma unroll
    for (int i = 0; i < 4; ++i) {
      const int s = (wave * 4 + i) * 64 + lane;     // 16B slot index
      const int mr = s >> 3;                        // row within 128
      const int kg = (s & 7) ^ (mr & 7);            // logical k-block (XOR swizzle)
      const unsigned short* srcA = A  + (size_t)(bm + mr) * K + k0 + kg * 8;
      const unsigned short* srcB = Bt + (size_t)(bn + mr) * K + k0 + kg * 8;
      __builtin_amdgcn_global_load_lds(
          (const __attribute__((address_space(1))) void*)srcA,
          (__attribute__((address_space(3))) void*)&As[(size_t)(wave * 4 + i) * 512], 16, 0, 0);
      __builtin_amdgcn_global_load_lds(
          (const __attribute__((address_space(1))) void*)srcB,
          (__attribute__((address_space(3))) void*)&Bs[(size_t)(wave * 4 + i) * 512], 16, 0, 0);
    }
    __syncthreads();
    #pragma unroll
    for (int ks = 0; ks < 2; ++ks) {
      const int kg = ks * 4 + (lane >> 4);
      short8 af[4], bfr[4];
      #pragma unroll
      for (int i = 0; i < 4; ++i) {
        const int m = wr + i * 16 + (lane & 15);
        af[i] = *(const short8*)&As[(m * 8 + (kg ^ (m & 7))) * 8];
      }
      #pragma unroll
      for (int j = 0; j < 4; ++j) {
        const int n = wc + j * 16 + (lane & 15);
        bfr[j] = *(const short8*)&Bs[(n * 8 + (kg ^ (n & 7))) * 8];
      }
      #pragma unroll
      for (int i = 0; i < 4; ++i)
        #pragma unroll
        for (int j = 0; j < 4; ++j)
          acc[i][j] = __builtin_amdgcn_mfma_f32_16x16x32_bf16(af[i], bfr[j], acc[i][j], 0, 0, 0);
    }
    __syncthreads();
  }

  const int lr = (lane >> 4) * 4, lc = lane & 15;
  #pragma unroll
  for (int i = 0; i < 4; ++i) {
    #pragma unroll
    for (int j = 0; j < 4; ++j) {
      const int n = bn + wc + j * 16 + lc;
      const float bv = bias[n];
      #pragma unroll
      for (int p = 0; p < 4; ++p) {
        const int m = bm + wr + i * 16 + lr + p;
        float val = acc[i][j][p] + bv;
        if (act) val = gelu_f(val);
        if (Cf) Cf[(size_t)m * N + n] = val;
        if (Cb) Cb[(size_t)m * N + n] = f2b(val);
      }
    }
  }
}

// ================= banded sliding-window attention =================
// block = (head, chunk), 256 threads: row r = t&127, half = t>>7 scans half the keys;
// halves merged via LDS online-softmax merge. Output bf16.
__global__ __launch_bounds__(256) void banded_attn_kernel(
    const float* __restrict__ qkv, const int* __restrict__ am,
    unsigned short* __restrict__ outb)
{
  const int h = blockIdx.x, nc = blockIdx.y;
  const int t = threadIdx.x, r = t & 127, half = t >> 7;
  const int s = nc * CHUNK + r;
  __shared__ float sm[128], sl[128];
  __shared__ float sacc[128][64];

  const float* qp = qkv + (size_t)s * QKV_N + h * DHEAD;
  float qr[64];
  #pragma unroll
  for (int d0 = 0; d0 < 64; d0 += 4) {
    const float4 t4 = *reinterpret_cast<const float4*>(qp + d0);
    qr[d0] = t4.x * 0.125f; qr[d0+1] = t4.y * 0.125f; qr[d0+2] = t4.z * 0.125f; qr[d0+3] = t4.w * 0.125f;
  }
  float m = -1e30f, l = 0.f;
  float acc[64];
  #pragma unroll
  for (int d = 0; d < 64; ++d) acc[d] = 0.f;

  const float* kbase_p = qkv + DMODEL + h * DHEAD;       // k segment
  const float* vbase_p = qkv + 2 * DMODEL + h * DHEAD;   // v segment

  if (half == 0 && am[0] > 0) {  // global CLS key (k row 0)
    float sc = 0.f;
    #pragma unroll
    for (int d0 = 0; d0 < 64; d0 += 4) {
      const float4 k4 = *reinterpret_cast<const float4*>(kbase_p + d0);
      sc = fmaf(qr[d0], k4.x, fmaf(qr[d0+1], k4.y, fmaf(qr[d0+2], k4.z, fmaf(qr[d0+3], k4.w, sc))));
    }
    m = sc; l = 1.f;
    #pragma unroll
    for (int d0 = 0; d0 < 64; d0 += 4) {
      const float4 v4 = *reinterpret_cast<const float4*>(vbase_p + d0);
      acc[d0] = v4.x; acc[d0+1] = v4.y; acc[d0+2] = v4.z; acc[d0+3] = v4.w;
    }
  }

  const int kb = nc * CHUNK - CHUNK;
  const int jbeg = half ? 192 : 0, jend = half ? 384 : 192;
  for (int j = jbeg; j < jend; ++j) {
    const int kj = kb + j;
    if (kj < 1 || kj >= S_LEN) continue;   // uniform branch
    const int diff = r + CHUNK - j;        // qi - kj
    const bool ok = (diff >= -128) && (diff <= 128) && (am[kj] > 0);
    float sc = 0.f;
    const float* kr = kbase_p + (size_t)kj * QKV_N;
    #pragma unroll
    for (int d0 = 0; d0 < 64; d0 += 4) {
      const float4 k4 = *reinterpret_cast<const float4*>(kr + d0);
      sc = fmaf(qr[d0], k4.x, fmaf(qr[d0+1], k4.y, fmaf(qr[d0+2], k4.z, fmaf(qr[d0+3], k4.w, sc))));
    }
    if (!ok) continue;
    const float newm = fmaxf(m, sc);
    const float corr = expf(m - newm);
    const float p = expf(sc - newm);
    l = l * corr + p;
    const float* vr = vbase_p + (size_t)kj * QKV_N;
    #pragma unroll
    for (int d0 = 0; d0 < 64; d0 += 4) {
      const float4 v4 = *reinterpret_cast<const float4*>(vr + d0);
      acc[d0]   = fmaf(acc[d0],   corr, p * v4.x);
      acc[d0+1] = fmaf(acc[d0+1], corr, p * v4.y);
      acc[d0+2] = fmaf(acc[d0+2], corr, p * v4.z);
      acc[d0+3] = fmaf(acc[d0+3], corr, p * v4.w);
    }
    m = newm;
  }

  if (half == 1) {
    sm[r] = m; sl[r] = l;
    #pragma unroll
    for (int d = 0; d < 64; ++d) sacc[r][d] = acc[d];
  }
  __syncthreads();
  if (half == 0) {
    const float m2 = sm[r], l2 = sl[r];
    const float M = fmaxf(m, m2);
    const float c1 = expf(m - M), c2 = expf(m2 - M);
    const float L = l * c1 + l2 * c2;
    const float rl = (L > 0.f) ? 1.f / L : 0.f;
    unsigned short* op = outb + (size_t)s * DMODEL + h * DHEAD;
    #pragma unroll
    for (int d0 = 0; d0 < 64; d0 += 2) {
      const float o0 = (acc[d0]   * c1 + sacc[r][d0]   * c2) * rl;
      const float o1 = (acc[d0+1] * c1 + sacc[r][d0+1] * c2) * rl;
      const unsigned int w = (unsigned int)f2b(o0) | ((unsigned int)f2b(o1) << 16);
      *reinterpret_cast<unsigned int*>(op + d0) = w;
    }
  }
}

// ================= global CLS row attention: partial (12 heads x 8 segments) + combine =================
__global__ __launch_bounds__(256) void glb_attn_partial_kernel(
    const float* __restrict__ qg0, const float* __restrict__ qkv,
    const int* __restrict__ am, float* __restrict__ part)
{
  const int h = blockIdx.x, g = blockIdx.y, t = threadIdx.x;
  const float* kg = qkv + 3 * DMODEL;
  const float* vg = qkv + 4 * DMODEL;
  __shared__ float sc[256];
  __shared__ float qs[64];
  __shared__ float red[4];
  __shared__ float pb[4][64];
  if (t < 64) qs[t] = qg0[h * DHEAD + t] * 0.125f;
  __syncthreads();
  const int s0 = g * 256 + t;
  float d = 0.f;
  const float* kr = kg + (size_t)s0 * QKV_N + h * DHEAD;
  #pragma unroll
  for (int d0 = 0; d0 < 64; d0 += 4)
    d += qs[d0]*kr[d0] + qs[d0+1]*kr[d0+1] + qs[d0+2]*kr[d0+2] + qs[d0+3]*kr[d0+3];
  const float mysc = (am[s0] > 0) ? d : -1e9f;
  float mx = mysc;
  #pragma unroll
  for (int off = 32; off; off >>= 1) mx = fmaxf(mx, __shfl_down(mx, off));
  if ((t & 63) == 0) red[t >> 6] = mx;
  __syncthreads();
  mx = fmaxf(fmaxf(red[0], red[1]), fmaxf(red[2], red[3]));
  __syncthreads();
  const float e = expf(mysc - mx);
  sc[t] = e;
  float sum = e;
  #pragma unroll
  for (int off = 32; off; off >>= 1) sum += __shfl_down(sum, off);
  if ((t & 63) == 0) red[t >> 6] = sum;
  __syncthreads();
  const float lsum = red[0] + red[1] + red[2] + red[3];
  // PV over this segment (unnormalized)
  const int dd = t & 63, grp = t >> 6;
  float pa = 0.f;
  for (int i = 0; i < 64; ++i) {
    const int li = grp * 64 + i;
    pa = fmaf(sc[li], vg[(size_t)(g * 256 + li) * QKV_N + h * DHEAD + dd], pa);
  }
  pb[grp][dd] = pa;
  __syncthreads();
  float* pr = part + (size_t)(h * 8 + g) * 66;
  if (t < 64) pr[2 + t] = pb[0][t] + pb[1][t] + pb[2][t] + pb[3][t];
  if (t == 0) { pr[0] = mx; pr[1] = lsum; }
}

__global__ __launch_bounds__(64) void glb_attn_combine_kernel(
    const float* __restrict__ part, unsigned short* __restrict__ outb)
{
  const int h = blockIdx.x, d = threadIdx.x;
  float M = -1e30f;
  for (int g = 0; g < 8; ++g) M = fmaxf(M, part[(size_t)(h * 8 + g) * 66]);
  float L = 0.f, o = 0.f;
  for (int g = 0; g < 8; ++g) {
    const float* pr = part + (size_t)(h * 8 + g) * 66;
    const float c = (pr[0] > -1e8f) ? expf(pr[0] - M) : 0.f;
    L += pr[1] * c;
    o += pr[2 + d] * c;
  }
  outb[h * DHEAD + d] = f2b(o / L);  // row 0
}

// ================= split-k GEMV: y[768] = act(x[768] @ W[768][768] + b) =================
__global__ __launch_bounds__(256) void gemv_partial_kernel(
    const float* __restrict__ xrow, const float* __restrict__ W, float* __restrict__ part)
{
  const int b = blockIdx.x, t = threadIdx.x;  // grid 16, k-chunk 48
  float s0 = 0.f, s1 = 0.f, s2 = 0.f;
  for (int kk = 0; kk < 48; ++kk) {
    const int k = b * 48 + kk;
    const float xv = xrow[k];
    const float* wr = W + (size_t)k * DMODEL;
    s0 = fmaf(xv, wr[t], s0);
    s1 = fmaf(xv, wr[t + 256], s1);
    s2 = fmaf(xv, wr[t + 512], s2);
  }
  part[b * DMODEL + t] = s0;
  part[b * DMODEL + t + 256] = s1;
  part[b * DMODEL + t + 512] = s2;
}

__global__ __launch_bounds__(256) void gemv_reduce_kernel(
    const float* __restrict__ part, const float* __restrict__ bias,
    float* __restrict__ y, int act)
{
  const int n = blockIdx.x * 256 + threadIdx.x;
  float s = bias[n];
  #pragma unroll
  for (int b = 0; b < 16; ++b) s += part[b * DMODEL + n];
  if (act) s = gelu_f(s);
  y[n] = s;
}

// ================= final head =================
__global__ __launch_bounds__(256) void head_final_kernel(
    const float* __restrict__ h2, const float* __restrict__ Wout,
    const float* __restrict__ bout, float* __restrict__ out)
{
  const int tid = threadIdx.x;
  __shared__ float red[4];
  float p = h2[tid]*Wout[tid] + h2[tid+256]*Wout[tid+256] + h2[tid+512]*Wout[tid+512];
  #pragma unroll
  for (int off = 32; off; off >>= 1) p += __shfl_down(p, off);
  if ((tid & 63) == 0) red[tid >> 6] = p;
  __syncthreads();
  if (tid == 0) {
    const float logit = red[0] + red[1] + red[2] + red[3] + bout[0];
    const float sig = 1.0f / (1.0f + expf(-logit));
    const unsigned int bits = __float_as_uint(sig);
    const unsigned int bf = (bits + 0x7FFFu + ((bits >> 16) & 1u)) >> 16;
    out[0] = __uint_as_float((bits & 0xFFFF0000u) | (bf & 0xFFFFu));
  }
}

extern "C" void kernel_launch(void* const* d_in, const int* in_sizes, int n_in,
                              void* d_out, int out_size, void* d_ws, size_t ws_size,
                              hipStream_t stream)
{
  const int*   ids  = (const int*)d_in[0];
  const int*   am   = (const int*)d_in[1];
  const float* wemb = (const float*)d_in[2];
  const float* pemb = (const float*)d_in[3];
  const float* emb_g = (const float*)d_in[4];
  const float* emb_b = (const float*)d_in[5];
  const float* Wq  = (const float*)d_in[6];
  const float* bq  = (const float*)d_in[7];
  const float* Wk  = (const float*)d_in[8];
  const float* bk  = (const float*)d_in[9];
  const float* Wv  = (const float*)d_in[10];
  const float* bv  = (const float*)d_in[11];
  const float* Wqg = (const float*)d_in[12];
  const float* bqg = (const float*)d_in[13];
  const float* Wkg = (const float*)d_in[14];
  const float* bkg = (const float*)d_in[15];
  const float* Wvg = (const float*)d_in[16];
  const float* bvg = (const float*)d_in[17];
  const float* Wo  = (const float*)d_in[18];
  const float* bo  = (const float*)d_in[19];
  const float* ln1g = (const float*)d_in[20];
  const float* ln1b = (const float*)d_in[21];
  const float* Wf1 = (const float*)d_in[22];
  const float* bf1 = (const float*)d_in[23];
  const float* Wf2 = (const float*)d_in[24];
  const float* bf2 = (const float*)d_in[25];
  const float* ln2g = (const float*)d_in[26];
  const float* ln2b = (const float*)d_in[27];
  const float* hng = (const float*)d_in[28];
  const float* hnb = (const float*)d_in[29];
  const float* W1  = (const float*)d_in[30];
  const float* b1  = (const float*)d_in[31];
  const float* W2  = (const float*)d_in[32];
  const float* b2  = (const float*)d_in[33];
  const float* Wout = (const float*)d_in[34];
  const float* bout = (const float*)d_in[35];

  char* wp = (char*)d_ws;
  auto alloc = [&](size_t bytes) -> void* {
    void* r = (void*)wp;
    wp += (bytes + 255) & ~(size_t)255;
    return r;
  };
  float*          x      = (float*)alloc((size_t)S_LEN * DMODEL * 4);
  unsigned short* xb     = (unsigned short*)alloc((size_t)S_LEN * DMODEL * 2);
  float*          qkv    = (float*)alloc((size_t)S_LEN * QKV_N * 4);
  unsigned short* attnb  = (unsigned short*)alloc((size_t)S_LEN * DMODEL * 2);
  float*          tmpf   = (float*)alloc((size_t)S_LEN * DMODEL * 4);
  unsigned short* tmpb   = (unsigned short*)alloc((size_t)S_LEN * FFDIM * 2);
  unsigned short* WqkvT  = (unsigned short*)alloc((size_t)5 * DMODEL * DMODEL * 2);
  unsigned short* WoT    = (unsigned short*)alloc((size_t)DMODEL * DMODEL * 2);
  unsigned short* Wf1T   = (unsigned short*)alloc((size_t)DMODEL * FFDIM * 2);
  unsigned short* Wf2T   = (unsigned short*)alloc((size_t)DMODEL * FFDIM * 2);
  float*          bqkv   = (float*)alloc((size_t)QKV_N * 4);
  float*          qg0    = (float*)alloc((size_t)DMODEL * 4);
  float*          gpart  = (float*)alloc((size_t)16 * DMODEL * 4);
  float*          glbp   = (float*)alloc((size_t)NHEAD * 8 * 66 * 4);
  float*          hb     = (float*)alloc((size_t)3 * DMODEL * 4);

  embed_ln_kernel<<<S_LEN, 256, 0, stream>>>(ids, wemb, pemb, emb_g, emb_b, x, xb);

  const dim3 blk32x8(32, 8);
  for (int l = 0; l < NLAYER; ++l) {
    const size_t wdd = (size_t)l * DMODEL * DMODEL;
    const size_t wdf = (size_t)l * DMODEL * FFDIM;
    const size_t vd  = (size_t)l * DMODEL;
    const size_t vf  = (size_t)l * FFDIM;

    conv6_kernel<<<dim3(24, 24, 6), blk32x8, 0, stream>>>(
        Wq + wdd, Wk + wdd, Wv + wdd, Wkg + wdd, Wvg + wdd, Wo + wdd,
        bq + vd, bk + vd, bv + vd, bkg + vd, bvg + vd, WqkvT, WoT, bqkv);
    conv_ffn_kernel<<<dim3(96, 24, 2), blk32x8, 0, stream>>>(Wf1 + wdf, Wf2 + wdf, Wf1T, Wf2T);

    // fused q|k|v|kg|vg projection: [2048,768] @ [768,3840]
    gemm_mfma_kernel<<<dim3(16, 30), 256, 0, stream>>>(
        xb, WqkvT, bqkv, qkv, (unsigned short*)nullptr, QKV_N, DMODEL, 0);

    gemv_partial_kernel<<<16, 256, 0, stream>>>(x, Wqg + wdd, gpart);
    gemv_reduce_kernel<<<3, 256, 0, stream>>>(gpart, bqg + vd, qg0, 0);

    banded_attn_kernel<<<dim3(NHEAD, NCHUNK), 256, 0, stream>>>(qkv, am, attnb);
    glb_attn_partial_kernel<<<dim3(NHEAD, 8), 256, 0, stream>>>(qg0, qkv, am, glbp);
    glb_attn_combine_kernel<<<NHEAD, 64, 0, stream>>>(glbp, attnb);

    gemm_mfma_kernel<<<dim3(16, 6), 256, 0, stream>>>(
        attnb, WoT, bo + vd, tmpf, (unsigned short*)nullptr, DMODEL, DMODEL, 0);
    add_ln_kernel<<<S_LEN, 256, 0, stream>>>(x, tmpf, ln1g + vd, ln1b + vd, xb);

    gemm_mfma_kernel<<<dim3(16, 24), 256, 0, stream>>>(
        xb, Wf1T, bf1 + vf, (float*)nullptr, tmpb, FFDIM, DMODEL, 1);
    gemm_mfma_kernel<<<dim3(16, 6), 256, 0, stream>>>(
        tmpb, Wf2T, bf2 + vd, tmpf, (unsigned short*)nullptr, DMODEL, FFDIM, 0);
    add_ln_kernel<<<S_LEN, 256, 0, stream>>>(x, tmpf, ln2g + vd, ln2b + vd, xb);
  }

  ln_vec_kernel<<<1, 256, 0, stream>>>(x, hng, hnb, hb);
  gemv_partial_kernel<<<16, 256, 0, stream>>>(hb, W1, gpart);
  gemv_reduce_kernel<<<3, 256, 0, stream>>>(gpart, b1, hb + DMODEL, 1);
  gemv_partial_kernel<<<16, 256, 0, stream>>>(hb + DMODEL, W2, gpart);
  gemv_reduce_kernel<<<3, 256, 0, stream>>>(gpart, b2, hb + 2 * DMODEL, 1);
  head_final_kernel<<<1, 256, 0, stream>>>(hb + 2 * DMODEL, Wout, bout, (float*)d_out);
}

// Round 3
// 2578.490 us; speedup vs baseline: 11.6618x; 2.7411x over previous
//
#include <hip/hip_runtime.h>
#include <math.h>

#define S_LEN 2048
#define DMODEL 768
#define NHEAD 12
#define DHEAD 64
#define NLAYER 12
#define FFDIM 3072
#define CHUNK 128
#define NCHUNK 16
#define QKV_N 3840   // q|k|v|kg|vg concatenated

typedef __attribute__((ext_vector_type(8))) short short8;
typedef __attribute__((ext_vector_type(4))) float f32x4;

__device__ __forceinline__ float gelu_f(float x) {
  return 0.5f * x * (1.0f + erff(x * 0.7071067811865476f));
}
// float -> bf16 bits (RNE)
__device__ __forceinline__ unsigned short f2b(float f) {
  unsigned int u = __float_as_uint(f);
  return (unsigned short)((u + 0x7FFFu + ((u >> 16) & 1u)) >> 16);
}

// ================= LayerNorm family (f32 math, bf16 copy) =================
__global__ __launch_bounds__(256) void embed_ln_kernel(
    const int* __restrict__ ids, const float* __restrict__ wemb,
    const float* __restrict__ pemb, const float* __restrict__ g,
    const float* __restrict__ b, float* __restrict__ x, unsigned short* __restrict__ xb)
{
  const int s = blockIdx.x, tid = threadIdx.x;
  __shared__ float red[4];
  const size_t wbase = (size_t)ids[s] * DMODEL;
  const size_t pbase = (size_t)s * DMODEL;
  float y0 = wemb[wbase + tid]       + pemb[pbase + tid];
  float y1 = wemb[wbase + tid + 256] + pemb[pbase + tid + 256];
  float y2 = wemb[wbase + tid + 512] + pemb[pbase + tid + 512];
  float sum = y0 + y1 + y2;
  #pragma unroll
  for (int off = 32; off; off >>= 1) sum += __shfl_down(sum, off);
  if ((tid & 63) == 0) red[tid >> 6] = sum;
  __syncthreads();
  const float mean = (red[0] + red[1] + red[2] + red[3]) * (1.0f / 768.0f);
  __syncthreads();
  float d0 = y0 - mean, d1 = y1 - mean, d2 = y2 - mean;
  float vs = d0*d0 + d1*d1 + d2*d2;
  #pragma unroll
  for (int off = 32; off; off >>= 1) vs += __shfl_down(vs, off);
  if ((tid & 63) == 0) red[tid >> 6] = vs;
  __syncthreads();
  const float rstd = rsqrtf((red[0]+red[1]+red[2]+red[3]) * (1.0f/768.0f) + 1e-5f);
  float o0 = d0 * rstd * g[tid]       + b[tid];
  float o1 = d1 * rstd * g[tid + 256] + b[tid + 256];
  float o2 = d2 * rstd * g[tid + 512] + b[tid + 512];
  x[pbase + tid] = o0; x[pbase + tid + 256] = o1; x[pbase + tid + 512] = o2;
  xb[pbase + tid] = f2b(o0); xb[pbase + tid + 256] = f2b(o1); xb[pbase + tid + 512] = f2b(o2);
}

__global__ __launch_bounds__(256) void add_ln_kernel(
    float* __restrict__ x, const float* __restrict__ t,
    const float* __restrict__ g, const float* __restrict__ b,
    unsigned short* __restrict__ xb)
{
  const int s = blockIdx.x, tid = threadIdx.x;
  __shared__ float red[4];
  const size_t base = (size_t)s * DMODEL;
  float y0 = x[base + tid]       + t[base + tid];
  float y1 = x[base + tid + 256] + t[base + tid + 256];
  float y2 = x[base + tid + 512] + t[base + tid + 512];
  float sum = y0 + y1 + y2;
  #pragma unroll
  for (int off = 32; off; off >>= 1) sum += __shfl_down(sum, off);
  if ((tid & 63) == 0) red[tid >> 6] = sum;
  __syncthreads();
  const float mean = (red[0] + red[1] + red[2] + red[3]) * (1.0f / 768.0f);
  __syncthreads();
  float d0 = y0 - mean, d1 = y1 - mean, d2 = y2 - mean;
  float vs = d0*d0 + d1*d1 + d2*d2;
  #pragma unroll
  for (int off = 32; off; off >>= 1) vs += __shfl_down(vs, off);
  if ((tid & 63) == 0) red[tid >> 6] = vs;
  __syncthreads();
  const float rstd = rsqrtf((red[0]+red[1]+red[2]+red[3]) * (1.0f/768.0f) + 1e-5f);
  float o0 = d0 * rstd * g[tid]       + b[tid];
  float o1 = d1 * rstd * g[tid + 256] + b[tid + 256];
  float o2 = d2 * rstd * g[tid + 512] + b[tid + 512];
  x[base + tid] = o0; x[base + tid + 256] = o1; x[base + tid + 512] = o2;
  xb[base + tid] = f2b(o0); xb[base + tid + 256] = f2b(o1); xb[base + tid + 512] = f2b(o2);
}

__global__ __launch_bounds__(256) void ln_vec_kernel(
    const float* __restrict__ in, const float* __restrict__ g,
    const float* __restrict__ b, float* __restrict__ out)
{
  const int tid = threadIdx.x;
  __shared__ float red[4];
  float y0 = in[tid], y1 = in[tid + 256], y2 = in[tid + 512];
  float sum = y0 + y1 + y2;
  #pragma unroll
  for (int off = 32; off; off >>= 1) sum += __shfl_down(sum, off);
  if ((tid & 63) == 0) red[tid >> 6] = sum;
  __syncthreads();
  const float mean = (red[0] + red[1] + red[2] + red[3]) * (1.0f / 768.0f);
  __syncthreads();
  float d0 = y0 - mean, d1 = y1 - mean, d2 = y2 - mean;
  float vs = d0*d0 + d1*d1 + d2*d2;
  #pragma unroll
  for (int off = 32; off; off >>= 1) vs += __shfl_down(vs, off);
  if ((tid & 63) == 0) red[tid >> 6] = vs;
  __syncthreads();
  const float rstd = rsqrtf((red[0]+red[1]+red[2]+red[3]) * (1.0f/768.0f) + 1e-5f);
  out[tid]       = d0 * rstd * g[tid]       + b[tid];
  out[tid + 256] = d1 * rstd * g[tid + 256] + b[tid + 256];
  out[tid + 512] = d2 * rstd * g[tid + 512] + b[tid + 512];
}

// ================= weight convert + transpose (f32 [K][N] -> bf16 [N][K]) =================
__global__ __launch_bounds__(256) void conv6_kernel(
    const float* __restrict__ W0, const float* __restrict__ W1, const float* __restrict__ W2,
    const float* __restrict__ W3, const float* __restrict__ W4, const float* __restrict__ W5,
    const float* __restrict__ b0, const float* __restrict__ b1, const float* __restrict__ b2,
    const float* __restrict__ b3, const float* __restrict__ b4,
    unsigned short* __restrict__ WqkvT, unsigned short* __restrict__ WoT,
    float* __restrict__ bqkv)
{
  const int z = blockIdx.z;
  const float* src = z==0?W0: z==1?W1: z==2?W2: z==3?W3: z==4?W4: W5;
  unsigned short* dst = (z < 5) ? (WqkvT + (size_t)z * DMODEL * DMODEL) : WoT;
  __shared__ float tbuf[32][33];
  const int n0 = blockIdx.x * 32, k0 = blockIdx.y * 32;
  const int tx = threadIdx.x, ty = threadIdx.y;  // block (32,8)
  #pragma unroll
  for (int r = ty; r < 32; r += 8)
    tbuf[r][tx] = src[(size_t)(k0 + r) * DMODEL + n0 + tx];
  __syncthreads();
  #pragma unroll
  for (int r = ty; r < 32; r += 8)
    dst[(size_t)(n0 + r) * DMODEL + k0 + tx] = f2b(tbuf[tx][r]);
  if (z < 5 && blockIdx.x == 0 && blockIdx.y == 0) {
    const float* bsrc = z==0?b0: z==1?b1: z==2?b2: z==3?b3: b4;
    const int t = ty * 32 + tx;
    for (int i = t; i < DMODEL; i += 256) bqkv[z * DMODEL + i] = bsrc[i];
  }
}

__global__ __launch_bounds__(256) void conv_ffn_kernel(
    const float* __restrict__ Wf1, const float* __restrict__ Wf2,
    unsigned short* __restrict__ Wf1T, unsigned short* __restrict__ Wf2T)
{
  const int z = blockIdx.z;
  __shared__ float tbuf[32][33];
  const float* src; unsigned short* dst; int Kd, Nd, n0, k0;
  if (z == 0) { src = Wf1; dst = Wf1T; Kd = DMODEL; Nd = FFDIM;
                n0 = blockIdx.x * 32; k0 = blockIdx.y * 32; }
  else        { src = Wf2; dst = Wf2T; Kd = FFDIM; Nd = DMODEL;
                n0 = blockIdx.y * 32; k0 = blockIdx.x * 32; }
  const int tx = threadIdx.x, ty = threadIdx.y;
  #pragma unroll
  for (int r = ty; r < 32; r += 8)
    tbuf[r][tx] = src[(size_t)(k0 + r) * Nd + n0 + tx];
  __syncthreads();
  #pragma unroll
  for (int r = ty; r < 32; r += 8)
    dst[(size_t)(n0 + r) * Kd + k0 + tx] = f2b(tbuf[tx][r]);
}

// ================= bf16 MFMA GEMM (128x128 tile, BK=64, swizzled LDS) =================
__global__ __launch_bounds__(256) void gemm_mfma_kernel(
    const unsigned short* __restrict__ A, const unsigned short* __restrict__ Bt,
    const float* __restrict__ bias, float* __restrict__ Cf,
    unsigned short* __restrict__ Cb, int N, int K, int act)
{
  __shared__ unsigned short As[8192];  // 1024 slots x 16B
  __shared__ unsigned short Bs[8192];
  const int tid = threadIdx.x, wave = tid >> 6, lane = tid & 63;
  const int bm = blockIdx.x * 128, bn = blockIdx.y * 128;
  const int wr = (wave >> 1) * 64, wc = (wave & 1) * 64;
  f32x4 acc[4][4];
  const f32x4 zz = {0.f, 0.f, 0.f, 0.f};
  #pragma unroll
  for (int i = 0; i < 4; ++i)
    #pragma unroll
    for (int j = 0; j < 4; ++j) acc[i][j] = zz;

  for (int k0 = 0; k0 < K; k0 += 64) {
    #pragma unroll
    for (int i = 0; i < 4; ++i) {
      const int s = (wave * 4 + i) * 64 + lane;     // 16B slot index
      const int mr = s >> 3;
      const int kg = (s & 7) ^ (mr & 7);
      const unsigned short* srcA = A  + (size_t)(bm + mr) * K + k0 + kg * 8;
      const unsigned short* srcB = Bt + (size_t)(bn + mr) * K + k0 + kg * 8;
      __builtin_amdgcn_global_load_lds(
          (const __attribute__((address_space(1))) void*)srcA,
          (__attribute__((address_space(3))) void*)&As[(size_t)(wave * 4 + i) * 512], 16, 0, 0);
      __builtin_amdgcn_global_load_lds(
          (const __attribute__((address_space(1))) void*)srcB,
          (__attribute__((address_space(3))) void*)&Bs[(size_t)(wave * 4 + i) * 512], 16, 0, 0);
    }
    __syncthreads();
    #pragma unroll
    for (int ks = 0; ks < 2; ++ks) {
      const int kg = ks * 4 + (lane >> 4);
      short8 af[4], bfr[4];
      #pragma unroll
      for (int i = 0; i < 4; ++i) {
        const int m = wr + i * 16 + (lane & 15);
        af[i] = *(const short8*)&As[(m * 8 + (kg ^ (m & 7))) * 8];
      }
      #pragma unroll
      for (int j = 0; j < 4; ++j) {
        const int n = wc + j * 16 + (lane & 15);
        bfr[j] = *(const short8*)&Bs[(n * 8 + (kg ^ (n & 7))) * 8];
      }
      #pragma unroll
      for (int i = 0; i < 4; ++i)
        #pragma unroll
        for (int j = 0; j < 4; ++j)
          acc[i][j] = __builtin_amdgcn_mfma_f32_16x16x32_bf16(af[i], bfr[j], acc[i][j], 0, 0, 0);
    }
    __syncthreads();
  }

  const int lr = (lane >> 4) * 4, lc = lane & 15;
  #pragma unroll
  for (int i = 0; i < 4; ++i) {
    #pragma unroll
    for (int j = 0; j < 4; ++j) {
      const int n = bn + wc + j * 16 + lc;
      const float bv = bias[n];
      #pragma unroll
      for (int p = 0; p < 4; ++p) {
        const int m = bm + wr + i * 16 + lr + p;
        float val = acc[i][j][p] + bv;
        if (act) val = gelu_f(val);
        if (Cf) Cf[(size_t)m * N + n] = val;
        if (Cb) Cb[(size_t)m * N + n] = f2b(val);
      }
    }
  }
}

// ================= banded sliding-window attention, MFMA flash =================
// block = (head h, chunk nc), 256 threads = 4 waves; wave owns 32 q-rows.
// Online softmax over [CLS | up to 3x128 banded keys]; S and PV on 16x16x32 bf16 MFMA.
__global__ __launch_bounds__(256) void banded_attn_mfma_kernel(
    const unsigned short* __restrict__ qkvb, const float* __restrict__ qkvf,
    const int* __restrict__ am, unsigned short* __restrict__ outb)
{
  const int h = blockIdx.x, nc = blockIdx.y;
  const int tid = threadIdx.x, wave = tid >> 6, lane = tid & 63;
  const int c = lane & 15, g = lane >> 4;

  __shared__ unsigned short Ks[8192];   // K tile, slot-swizzled (16 KB)
  __shared__ unsigned short Vt[8192];   // V^T tile [dim][key], slot-swizzled (16 KB)
  __shared__ unsigned short Ps[16384];  // P tile [qrow][key], slot-swizzled (32 KB)
  __shared__ float smcls[128];
  __shared__ float sv0[64];
  __shared__ int   sam[128];

  // ---- CLS score (f32) + V0 staging ----
  if (tid < 64) sv0[tid] = qkvf[2 * DMODEL + h * DHEAD + tid];
  if (tid < 128) {
    const int qrow = nc * CHUNK + tid;
    const float* qp = qkvf + (size_t)qrow * QKV_N + h * DHEAD;
    const float* k0 = qkvf + DMODEL + h * DHEAD;
    float d = 0.f;
    #pragma unroll
    for (int dd = 0; dd < 64; dd += 4) {
      const float4 a4 = *(const float4*)(qp + dd);
      const float4 b4 = *(const float4*)(k0 + dd);
      d += a4.x*b4.x + a4.y*b4.y + a4.z*b4.z + a4.w*b4.w;
    }
    smcls[tid] = (am[0] > 0) ? d * 0.125f : -1e9f;
  }

  // ---- Q fragments in registers ----
  short8 af[2][2];
  #pragma unroll
  for (int i = 0; i < 2; ++i)
    #pragma unroll
    for (int ks = 0; ks < 2; ++ks) {
      const int qrow = nc * CHUNK + wave * 32 + i * 16 + c;
      af[i][ks] = *(const short8*)(qkvb + (size_t)qrow * QKV_N + h * DHEAD + (ks * 4 + g) * 8);
    }

  __syncthreads();

  float mrow[2][4], lrow[2][4];
  f32x4 acc_o[2][4];
  #pragma unroll
  for (int i = 0; i < 2; ++i)
    #pragma unroll
    for (int p = 0; p < 4; ++p) {
      mrow[i][p] = smcls[wave * 32 + i * 16 + g * 4 + p];
      lrow[i][p] = 1.f;
    }
  #pragma unroll
  for (int i = 0; i < 2; ++i)
    #pragma unroll
    for (int j = 0; j < 4; ++j) {
      const float v0 = sv0[j * 16 + c];
      acc_o[i][j][0] = v0; acc_o[i][j][1] = v0; acc_o[i][j][2] = v0; acc_o[i][j][3] = v0;
    }

  for (int kci = 0; kci < 3; ++kci) {
    const int ck = nc - 1 + kci;
    if (ck < 0 || ck > 15) continue;   // out-of-range chunk: reference contribution is exp->0
    __syncthreads();                   // previous tile fully consumed

    // ---- stage K tile via global_load_lds (swizzled slots) ----
    #pragma unroll
    for (int it = 0; it < 4; ++it) {
      const int sidx = it * 256 + tid;
      const int mr = sidx >> 3;
      const int kg = (sidx & 7) ^ (mr & 7);
      const unsigned short* src = qkvb + (size_t)(ck * CHUNK + mr) * QKV_N + DMODEL + h * DHEAD + kg * 8;
      __builtin_amdgcn_global_load_lds(
          (const __attribute__((address_space(1))) void*)src,
          (__attribute__((address_space(3))) void*)&Ks[(size_t)(it * 256 + wave * 64) * 8], 16, 0, 0);
    }
    // ---- stage V^T tile (reg-staged, pair-packed b32 writes) ----
    {
      const int kp = tid & 63, dh = tid >> 6;
      const unsigned short* v0p = qkvb + (size_t)(ck * CHUNK + 2 * kp) * QKV_N + 2 * DMODEL + h * DHEAD + dh * 16;
      const short8 a0 = *(const short8*)(v0p);
      const short8 a1 = *(const short8*)(v0p + 8);
      const short8 b0 = *(const short8*)(v0p + QKV_N);
      const short8 b1 = *(const short8*)(v0p + QKV_N + 8);
      #pragma unroll
      for (int dd = 0; dd < 16; ++dd) {
        const int dim = dh * 16 + dd;
        const unsigned short lo = (unsigned short)(dd < 8 ? a0[dd] : a1[dd - 8]);
        const unsigned short hi = (unsigned short)(dd < 8 ? b0[dd] : b1[dd - 8]);
        const unsigned int w = (unsigned int)lo | ((unsigned int)hi << 16);
        const int si = dim * 128 + (((kp >> 2) ^ (dim & 7)) << 3) + ((kp & 3) << 1);
        *(unsigned int*)&Vt[si] = w;
      }
    }
    if (tid < 128) sam[tid] = am[ck * CHUNK + tid];
    __syncthreads();

    // ---- S = Q @ K^T ----
    f32x4 accs[2][8];
    const f32x4 zz = {0.f, 0.f, 0.f, 0.f};
    #pragma unroll
    for (int i = 0; i < 2; ++i)
      #pragma unroll
      for (int j = 0; j < 8; ++j) accs[i][j] = zz;
    #pragma unroll
    for (int ks = 0; ks < 2; ++ks) {
      const int kg = ks * 4 + g;
      short8 bfr[8];
      #pragma unroll
      for (int j = 0; j < 8; ++j) {
        const int jj = j * 16 + c;
        bfr[j] = *(const short8*)&Ks[(jj * 8 + (kg ^ (jj & 7))) * 8];
      }
      #pragma unroll
      for (int i = 0; i < 2; ++i)
        #pragma unroll
        for (int j = 0; j < 8; ++j)
          accs[i][j] = __builtin_amdgcn_mfma_f32_16x16x32_bf16(af[i][ks], bfr[j], accs[i][j], 0, 0, 0);
    }

    // ---- mask + online softmax + P write ----
    #pragma unroll
    for (int i = 0; i < 2; ++i) {
      #pragma unroll
      for (int p = 0; p < 4; ++p) {
        const int mloc = wave * 32 + i * 16 + g * 4 + p;
        const int qi = nc * CHUNK + mloc;
        float sv[8];
        float rmax = -1e30f;
        #pragma unroll
        for (int j = 0; j < 8; ++j) {
          const int jj = j * 16 + c;
          const int kj = ck * CHUNK + jj;
          const int diff = qi - kj;
          const bool ok = (diff <= 128) && (diff >= -128) && (kj != 0) && (sam[jj] > 0);
          const float s = ok ? accs[i][j][p] * 0.125f : -1e9f;
          sv[j] = s;
          rmax = fmaxf(rmax, s);
        }
        rmax = fmaxf(rmax, __shfl_xor(rmax, 1));
        rmax = fmaxf(rmax, __shfl_xor(rmax, 2));
        rmax = fmaxf(rmax, __shfl_xor(rmax, 4));
        rmax = fmaxf(rmax, __shfl_xor(rmax, 8));
        const float mnew = fmaxf(mrow[i][p], rmax);
        const float corr = __expf(mrow[i][p] - mnew);
        float psum = 0.f;
        #pragma unroll
        for (int j = 0; j < 8; ++j) {
          const float pv = __expf(sv[j] - mnew);
          sv[j] = pv;
          psum += pv;
        }
        psum += __shfl_xor(psum, 1);
        psum += __shfl_xor(psum, 2);
        psum += __shfl_xor(psum, 4);
        psum += __shfl_xor(psum, 8);
        lrow[i][p] = lrow[i][p] * corr + psum;
        mrow[i][p] = mnew;
        #pragma unroll
        for (int j = 0; j < 4; ++j) acc_o[i][j][p] *= corr;
        #pragma unroll
        for (int j = 0; j < 8; ++j) {
          const int key = j * 16 + c;
          const int kslot = key >> 3;
          Ps[mloc * 128 + ((kslot ^ (mloc & 7)) << 3) + (key & 7)] = f2b(sv[j]);
        }
      }
    }
    // wave-private P rows: drain LDS writes before cross-lane reads (no block barrier needed)
    asm volatile("s_waitcnt lgkmcnt(0)" ::: "memory");

    // ---- O += P @ V ----
    #pragma unroll
    for (int ks2 = 0; ks2 < 4; ++ks2) {
      const int kg2 = ks2 * 4 + g;
      short8 pa[2], vb[4];
      #pragma unroll
      for (int i = 0; i < 2; ++i) {
        const int row = wave * 32 + i * 16 + c;
        pa[i] = *(const short8*)&Ps[row * 128 + ((kg2 ^ (row & 7)) << 3)];
      }
      #pragma unroll
      for (int j = 0; j < 4; ++j) {
        const int n = j * 16 + c;
        vb[j] = *(const short8*)&Vt[n * 128 + ((kg2 ^ (n & 7)) << 3)];
      }
      #pragma unroll
      for (int i = 0; i < 2; ++i)
        #pragma unroll
        for (int j = 0; j < 4; ++j)
          acc_o[i][j] = __builtin_amdgcn_mfma_f32_16x16x32_bf16(pa[i], vb[j], acc_o[i][j], 0, 0, 0);
    }
  }

  // ---- finalize ----
  #pragma unroll
  for (int i = 0; i < 2; ++i) {
    #pragma unroll
    for (int p = 0; p < 4; ++p) {
      const float rl = (lrow[i][p] > 0.f) ? 1.f / lrow[i][p] : 0.f;
      const int row = nc * CHUNK + wave * 32 + i * 16 + g * 4 + p;
      #pragma unroll
      for (int j = 0; j < 4; ++j)
        outb[(size_t)row * DMODEL + h * DHEAD + j * 16 + c] = f2b(acc_o[i][j][p] * rl);
    }
  }
}

// ================= global CLS row attention: partials + combine =================
__global__ __launch_bounds__(256) void glb_attn_partial_kernel(
    const float* __restrict__ qg0, const float* __restrict__ qkv,
    const int* __restrict__ am, float* __restrict__ part)
{
  const int h = blockIdx.x, g = blockIdx.y, t = threadIdx.x;
  const float* kg = qkv + 3 * DMODEL;
  const float* vg = qkv + 4 * DMODEL;
  __shared__ float sc[256];
  __shared__ float qs[64];
  __shared__ float red[4];
  __shared__ float pb[4][64];
  if (t < 64) qs[t] = qg0[h * DHEAD + t] * 0.125f;
  __syncthreads();
  const int s0 = g * 256 + t;
  float d = 0.f;
  const float* kr = kg + (size_t)s0 * QKV_N + h * DHEAD;
  #pragma unroll
  for (int d0 = 0; d0 < 64; d0 += 4)
    d += qs[d0]*kr[d0] + qs[d0+1]*kr[d0+1] + qs[d0+2]*kr[d0+2] + qs[d0+3]*kr[d0+3];
  const float mysc = (am[s0] > 0) ? d : -1e9f;
  float mx = mysc;
  #pragma unroll
  for (int off = 32; off; off >>= 1) mx = fmaxf(mx, __shfl_down(mx, off));
  if ((t & 63) == 0) red[t >> 6] = mx;
  __syncthreads();
  mx = fmaxf(fmaxf(red[0], red[1]), fmaxf(red[2], red[3]));
  __syncthreads();
  const float e = expf(mysc - mx);
  sc[t] = e;
  float sum = e;
  #pragma unroll
  for (int off = 32; off; off >>= 1) sum += __shfl_down(sum, off);
  if ((t & 63) == 0) red[t >> 6] = sum;
  __syncthreads();
  const float lsum = red[0] + red[1] + red[2] + red[3];
  const int dd = t & 63, grp = t >> 6;
  float pa = 0.f;
  for (int i = 0; i < 64; ++i) {
    const int li = grp * 64 + i;
    pa = fmaf(sc[li], vg[(size_t)(g * 256 + li) * QKV_N + h * DHEAD + dd], pa);
  }
  pb[grp][dd] = pa;
  __syncthreads();
  float* pr = part + (size_t)(h * 8 + g) * 66;
  if (t < 64) pr[2 + t] = pb[0][t] + pb[1][t] + pb[2][t] + pb[3][t];
  if (t == 0) { pr[0] = mx; pr[1] = lsum; }
}

__global__ __launch_bounds__(64) void glb_attn_combine_kernel(
    const float* __restrict__ part, unsigned short* __restrict__ outb)
{
  const int h = blockIdx.x, d = threadIdx.x;
  float M = -1e30f;
  for (int g = 0; g < 8; ++g) M = fmaxf(M, part[(size_t)(h * 8 + g) * 66]);
  float L = 0.f, o = 0.f;
  for (int g = 0; g < 8; ++g) {
    const float* pr = part + (size_t)(h * 8 + g) * 66;
    const float cc = (pr[0] > -1e8f) ? expf(pr[0] - M) : 0.f;
    L += pr[1] * cc;
    o += pr[2 + d] * cc;
  }
  outb[h * DHEAD + d] = f2b(o / L);
}

// ================= split-k GEMV =================
__global__ __launch_bounds__(256) void gemv_partial_kernel(
    const float* __restrict__ xrow, const float* __restrict__ W, float* __restrict__ part)
{
  const int b = blockIdx.x, t = threadIdx.x;
  float s0 = 0.f, s1 = 0.f, s2 = 0.f;
  for (int kk = 0; kk < 48; ++kk) {
    const int k = b * 48 + kk;
    const float xv = xrow[k];
    const float* wr = W + (size_t)k * DMODEL;
    s0 = fmaf(xv, wr[t], s0);
    s1 = fmaf(xv, wr[t + 256], s1);
    s2 = fmaf(xv, wr[t + 512], s2);
  }
  part[b * DMODEL + t] = s0;
  part[b * DMODEL + t + 256] = s1;
  part[b * DMODEL + t + 512] = s2;
}

__global__ __launch_bounds__(256) void gemv_reduce_kernel(
    const float* __restrict__ part, const float* __restrict__ bias,
    float* __restrict__ y, int act)
{
  const int n = blockIdx.x * 256 + threadIdx.x;
  float s = bias[n];
  #pragma unroll
  for (int b = 0; b < 16; ++b) s += part[b * DMODEL + n];
  if (act) s = gelu_f(s);
  y[n] = s;
}

// ================= final head =================
__global__ __launch_bounds__(256) void head_final_kernel(
    const float* __restrict__ h2, const float* __restrict__ Wout,
    const float* __restrict__ bout, float* __restrict__ out)
{
  const int tid = threadIdx.x;
  __shared__ float red[4];
  float p = h2[tid]*Wout[tid] + h2[tid+256]*Wout[tid+256] + h2[tid+512]*Wout[tid+512];
  #pragma unroll
  for (int off = 32; off; off >>= 1) p += __shfl_down(p, off);
  if ((tid & 63) == 0) red[tid >> 6] = p;
  __syncthreads();
  if (tid == 0) {
    const float logit = red[0] + red[1] + red[2] + red[3] + bout[0];
    const float sig = 1.0f / (1.0f + expf(-logit));
    const unsigned int bits = __float_as_uint(sig);
    const unsigned int bf = (bits + 0x7FFFu + ((bits >> 16) & 1u)) >> 16;
    out[0] = __uint_as_float((bits & 0xFFFF0000u) | (bf & 0xFFFFu));
  }
}

extern "C" void kernel_launch(void* const* d_in, const int* in_sizes, int n_in,
                              void* d_out, int out_size, void* d_ws, size_t ws_size,
                              hipStream_t stream)
{
  const int*   ids  = (const int*)d_in[0];
  const int*   am   = (const int*)d_in[1];
  const float* wemb = (const float*)d_in[2];
  const float* pemb = (const float*)d_in[3];
  const float* emb_g = (const float*)d_in[4];
  const float* emb_b = (const float*)d_in[5];
  const float* Wq  = (const float*)d_in[6];
  const float* bq  = (const float*)d_in[7];
  const float* Wk  = (const float*)d_in[8];
  const float* bk  = (const float*)d_in[9];
  const float* Wv  = (const float*)d_in[10];
  const float* bv  = (const float*)d_in[11];
  const float* Wqg = (const float*)d_in[12];
  const float* bqg = (const float*)d_in[13];
  const float* Wkg = (const float*)d_in[14];
  const float* bkg = (const float*)d_in[15];
  const float* Wvg = (const float*)d_in[16];
  const float* bvg = (const float*)d_in[17];
  const float* Wo  = (const float*)d_in[18];
  const float* bo  = (const float*)d_in[19];
  const float* ln1g = (const float*)d_in[20];
  const float* ln1b = (const float*)d_in[21];
  const float* Wf1 = (const float*)d_in[22];
  const float* bf1 = (const float*)d_in[23];
  const float* Wf2 = (const float*)d_in[24];
  const float* bf2 = (const float*)d_in[25];
  const float* ln2g = (const float*)d_in[26];
  const float* ln2b = (const float*)d_in[27];
  const float* hng = (const float*)d_in[28];
  const float* hnb = (const float*)d_in[29];
  const float* W1  = (const float*)d_in[30];
  const float* b1  = (const float*)d_in[31];
  const float* W2  = (const float*)d_in[32];
  const float* b2  = (const float*)d_in[33];
  const float* Wout = (const float*)d_in[34];
  const float* bout = (const float*)d_in[35];

  char* wp = (char*)d_ws;
  auto alloc = [&](size_t bytes) -> void* {
    void* r = (void*)wp;
    wp += (bytes + 255) & ~(size_t)255;
    return r;
  };
  float*          x      = (float*)alloc((size_t)S_LEN * DMODEL * 4);
  unsigned short* xb     = (unsigned short*)alloc((size_t)S_LEN * DMODEL * 2);
  float*          qkv    = (float*)alloc((size_t)S_LEN * QKV_N * 4);
  unsigned short* qkvb   = (unsigned short*)alloc((size_t)S_LEN * QKV_N * 2);
  unsigned short* attnb  = (unsigned short*)alloc((size_t)S_LEN * DMODEL * 2);
  unsigned short* tmpb   = (unsigned short*)alloc((size_t)S_LEN * FFDIM * 2);
  unsigned short* WqkvT  = (unsigned short*)alloc((size_t)5 * DMODEL * DMODEL * 2);
  unsigned short* WoT    = (unsigned short*)alloc((size_t)DMODEL * DMODEL * 2);
  unsigned short* Wf1T   = (unsigned short*)alloc((size_t)DMODEL * FFDIM * 2);
  unsigned short* Wf2T   = (unsigned short*)alloc((size_t)DMODEL * FFDIM * 2);
  float*          bqkv   = (float*)alloc((size_t)QKV_N * 4);
  float*          qg0    = (float*)alloc((size_t)DMODEL * 4);
  float*          gpart  = (float*)alloc((size_t)16 * DMODEL * 4);
  float*          glbp   = (float*)alloc((size_t)NHEAD * 8 * 66 * 4);
  float*          hb     = (float*)alloc((size_t)3 * DMODEL * 4);
  // tmpf (f32 GEMM output for residual) aliases qkv: qkv is dead once the
  // attention kernels of the current layer have consumed it, which is before
  // the Wo GEMM writes tmpf. Next layer's QKV GEMM rewrites qkv fully.
  float* tmpf = qkv;

  embed_ln_kernel<<<S_LEN, 256, 0, stream>>>(ids, wemb, pemb, emb_g, emb_b, x, xb);

  const dim3 blk32x8(32, 8);
  for (int l = 0; l < NLAYER; ++l) {
    const size_t wdd = (size_t)l * DMODEL * DMODEL;
    const size_t wdf = (size_t)l * DMODEL * FFDIM;
    const size_t vd  = (size_t)l * DMODEL;
    const size_t vf  = (size_t)l * FFDIM;

    conv6_kernel<<<dim3(24, 24, 6), blk32x8, 0, stream>>>(
        Wq + wdd, Wk + wdd, Wv + wdd, Wkg + wdd, Wvg + wdd, Wo + wdd,
        bq + vd, bk + vd, bv + vd, bkg + vd, bvg + vd, WqkvT, WoT, bqkv);
    conv_ffn_kernel<<<dim3(96, 24, 2), blk32x8, 0, stream>>>(Wf1 + wdf, Wf2 + wdf, Wf1T, Wf2T);

    // fused q|k|v|kg|vg projection: [2048,768] @ [768,3840] -> f32 + bf16
    gemm_mfma_kernel<<<dim3(16, 30), 256, 0, stream>>>(
        xb, WqkvT, bqkv, qkv, qkvb, QKV_N, DMODEL, 0);

    gemv_partial_kernel<<<16, 256, 0, stream>>>(x, Wqg + wdd, gpart);
    gemv_reduce_kernel<<<3, 256, 0, stream>>>(gpart, bqg + vd, qg0, 0);

    banded_attn_mfma_kernel<<<dim3(NHEAD, NCHUNK), 256, 0, stream>>>(qkvb, qkv, am, attnb);
    glb_attn_partial_kernel<<<dim3(NHEAD, 8), 256, 0, stream>>>(qg0, qkv, am, glbp);
    glb_attn_combine_kernel<<<NHEAD, 64, 0, stream>>>(glbp, attnb);

    gemm_mfma_kernel<<<dim3(16, 6), 256, 0, stream>>>(
        attnb, WoT, bo + vd, tmpf, (unsigned short*)nullptr, DMODEL, DMODEL, 0);
    add_ln_kernel<<<S_LEN, 256, 0, stream>>>(x, tmpf, ln1g + vd, ln1b + vd, xb);

    gemm_mfma_kernel<<<dim3(16, 24), 256, 0, stream>>>(
        xb, Wf1T, bf1 + vf, (float*)nullptr, tmpb, FFDIM, DMODEL, 1);
    gemm_mfma_kernel<<<dim3(16, 6), 256, 0, stream>>>(
        tmpb, Wf2T, bf2 + vd, tmpf, (unsigned short*)nullptr, DMODEL, FFDIM, 0);
    add_ln_kernel<<<S_LEN, 256, 0, stream>>>(x, tmpf, ln2g + vd, ln2b + vd, xb);
  }

  ln_vec_kernel<<<1, 256, 0, stream>>>(x, hng, hnb, hb);
  gemv_partial_kernel<<<16, 256, 0, stream>>>(hb, W1, gpart);
  gemv_reduce_kernel<<<3, 256, 0, stream>>>(gpart, b1, hb + DMODEL, 1);
  gemv_partial_kernel<<<16, 256, 0, stream>>>(hb + DMODEL, W2, gpart);
  gemv_reduce_kernel<<<3, 256, 0, stream>>>(gpart, b2, hb + 2 * DMODEL, 1);
  head_final_kernel<<<1, 256, 0, stream>>>(hb + 2 * DMODEL, Wout, bout, (float*)d_out);
}

// Round 4
// 2497.881 us; speedup vs baseline: 12.0382x; 1.0323x over previous
//
#include <hip/hip_runtime.h>
#include <math.h>

#define S_LEN 2048
#define DMODEL 768
#define NHEAD 12
#define DHEAD 64
#define NLAYER 12
#define FFDIM 3072
#define CHUNK 128
#define NCHUNK 16
#define QKV_N 3840   // q|k|v|kg|vg concatenated
#define DD (DMODEL * DMODEL)
#define DF (DMODEL * FFDIM)

typedef __attribute__((ext_vector_type(8))) short short8;
typedef __attribute__((ext_vector_type(4))) float f32x4;

__device__ __forceinline__ float gelu_f(float x) {
  return 0.5f * x * (1.0f + erff(x * 0.7071067811865476f));
}
// float -> bf16 bits (RNE)
__device__ __forceinline__ unsigned short f2b(float f) {
  unsigned int u = __float_as_uint(f);
  return (unsigned short)((u + 0x7FFFu + ((u >> 16) & 1u)) >> 16);
}
__device__ __forceinline__ float b2f(unsigned short u) {
  return __uint_as_float((unsigned int)u << 16);
}

// ================= LayerNorm family (f32 math, bf16 copy) =================
__global__ __launch_bounds__(256) void embed_ln_kernel(
    const int* __restrict__ ids, const float* __restrict__ wemb,
    const float* __restrict__ pemb, const float* __restrict__ g,
    const float* __restrict__ b, float* __restrict__ x, unsigned short* __restrict__ xb)
{
  const int s = blockIdx.x, tid = threadIdx.x;
  __shared__ float red[4];
  const size_t wbase = (size_t)ids[s] * DMODEL;
  const size_t pbase = (size_t)s * DMODEL;
  float y0 = wemb[wbase + tid]       + pemb[pbase + tid];
  float y1 = wemb[wbase + tid + 256] + pemb[pbase + tid + 256];
  float y2 = wemb[wbase + tid + 512] + pemb[pbase + tid + 512];
  float sum = y0 + y1 + y2;
  #pragma unroll
  for (int off = 32; off; off >>= 1) sum += __shfl_down(sum, off);
  if ((tid & 63) == 0) red[tid >> 6] = sum;
  __syncthreads();
  const float mean = (red[0] + red[1] + red[2] + red[3]) * (1.0f / 768.0f);
  __syncthreads();
  float d0 = y0 - mean, d1 = y1 - mean, d2 = y2 - mean;
  float vs = d0*d0 + d1*d1 + d2*d2;
  #pragma unroll
  for (int off = 32; off; off >>= 1) vs += __shfl_down(vs, off);
  if ((tid & 63) == 0) red[tid >> 6] = vs;
  __syncthreads();
  const float rstd = rsqrtf((red[0]+red[1]+red[2]+red[3]) * (1.0f/768.0f) + 1e-5f);
  float o0 = d0 * rstd * g[tid]       + b[tid];
  float o1 = d1 * rstd * g[tid + 256] + b[tid + 256];
  float o2 = d2 * rstd * g[tid + 512] + b[tid + 512];
  x[pbase + tid] = o0; x[pbase + tid + 256] = o1; x[pbase + tid + 512] = o2;
  xb[pbase + tid] = f2b(o0); xb[pbase + tid + 256] = f2b(o1); xb[pbase + tid + 512] = f2b(o2);
}

__global__ __launch_bounds__(256) void add_ln_kernel(
    float* __restrict__ x, const float* __restrict__ t,
    const float* __restrict__ g, const float* __restrict__ b,
    unsigned short* __restrict__ xb)
{
  const int s = blockIdx.x, tid = threadIdx.x;
  __shared__ float red[4];
  const size_t base = (size_t)s * DMODEL;
  float y0 = x[base + tid]       + t[base + tid];
  float y1 = x[base + tid + 256] + t[base + tid + 256];
  float y2 = x[base + tid + 512] + t[base + tid + 512];
  float sum = y0 + y1 + y2;
  #pragma unroll
  for (int off = 32; off; off >>= 1) sum += __shfl_down(sum, off);
  if ((tid & 63) == 0) red[tid >> 6] = sum;
  __syncthreads();
  const float mean = (red[0] + red[1] + red[2] + red[3]) * (1.0f / 768.0f);
  __syncthreads();
  float d0 = y0 - mean, d1 = y1 - mean, d2 = y2 - mean;
  float vs = d0*d0 + d1*d1 + d2*d2;
  #pragma unroll
  for (int off = 32; off; off >>= 1) vs += __shfl_down(vs, off);
  if ((tid & 63) == 0) red[tid >> 6] = vs;
  __syncthreads();
  const float rstd = rsqrtf((red[0]+red[1]+red[2]+red[3]) * (1.0f/768.0f) + 1e-5f);
  float o0 = d0 * rstd * g[tid]       + b[tid];
  float o1 = d1 * rstd * g[tid + 256] + b[tid + 256];
  float o2 = d2 * rstd * g[tid + 512] + b[tid + 512];
  x[base + tid] = o0; x[base + tid + 256] = o1; x[base + tid + 512] = o2;
  xb[base + tid] = f2b(o0); xb[base + tid + 256] = f2b(o1); xb[base + tid + 512] = f2b(o2);
}

__global__ __launch_bounds__(256) void ln_vec_kernel(
    const float* __restrict__ in, const float* __restrict__ g,
    const float* __restrict__ b, float* __restrict__ out)
{
  const int tid = threadIdx.x;
  __shared__ float red[4];
  float y0 = in[tid], y1 = in[tid + 256], y2 = in[tid + 512];
  float sum = y0 + y1 + y2;
  #pragma unroll
  for (int off = 32; off; off >>= 1) sum += __shfl_down(sum, off);
  if ((tid & 63) == 0) red[tid >> 6] = sum;
  __syncthreads();
  const float mean = (red[0] + red[1] + red[2] + red[3]) * (1.0f / 768.0f);
  __syncthreads();
  float d0 = y0 - mean, d1 = y1 - mean, d2 = y2 - mean;
  float vs = d0*d0 + d1*d1 + d2*d2;
  #pragma unroll
  for (int off = 32; off; off >>= 1) vs += __shfl_down(vs, off);
  if ((tid & 63) == 0) red[tid >> 6] = vs;
  __syncthreads();
  const float rstd = rsqrtf((red[0]+red[1]+red[2]+red[3]) * (1.0f/768.0f) + 1e-5f);
  out[tid]       = d0 * rstd * g[tid]       + b[tid];
  out[tid + 256] = d1 * rstd * g[tid + 256] + b[tid + 256];
  out[tid + 512] = d2 * rstd * g[tid + 512] + b[tid + 512];
}

// ====== one-shot weight convert+transpose, ALL layers (f32 [K][N] -> bf16 [N][K]) ======
__global__ __launch_bounds__(256) void conv_all_dd_kernel(
    const float* __restrict__ Wq, const float* __restrict__ Wk, const float* __restrict__ Wv,
    const float* __restrict__ Wkg, const float* __restrict__ Wvg, const float* __restrict__ Wo,
    const float* __restrict__ bq, const float* __restrict__ bk, const float* __restrict__ bv,
    const float* __restrict__ bkg, const float* __restrict__ bvg,
    unsigned short* __restrict__ WqkvT, unsigned short* __restrict__ WoT,
    float* __restrict__ bqkv)
{
  const int z = blockIdx.z, layer = z / 6, mat = z % 6;
  const size_t off = (size_t)layer * DD;
  const float* src = (mat==0?Wq: mat==1?Wk: mat==2?Wv: mat==3?Wkg: mat==4?Wvg: Wo) + off;
  unsigned short* dst = (mat < 5)
      ? (WqkvT + (size_t)layer * 5 * DD + (size_t)mat * DD)
      : (WoT + off);
  __shared__ float tbuf[32][33];
  const int n0 = blockIdx.x * 32, k0 = blockIdx.y * 32;
  const int tx = threadIdx.x, ty = threadIdx.y;  // block (32,8)
  #pragma unroll
  for (int r = ty; r < 32; r += 8)
    tbuf[r][tx] = src[(size_t)(k0 + r) * DMODEL + n0 + tx];
  __syncthreads();
  #pragma unroll
  for (int r = ty; r < 32; r += 8)
    dst[(size_t)(n0 + r) * DMODEL + k0 + tx] = f2b(tbuf[tx][r]);
  if (mat < 5 && blockIdx.x == 0 && blockIdx.y == 0) {
    const float* bs = (mat==0?bq: mat==1?bk: mat==2?bv: mat==3?bkg: bvg) + (size_t)layer * DMODEL;
    const int t = ty * 32 + tx;
    for (int i = t; i < DMODEL; i += 256) bqkv[(size_t)layer * QKV_N + mat * DMODEL + i] = bs[i];
  }
}

__global__ __launch_bounds__(256) void conv_all_ffn_kernel(
    const float* __restrict__ Wf1, const float* __restrict__ Wf2,
    unsigned short* __restrict__ Wf1T, unsigned short* __restrict__ Wf2T)
{
  const int z = blockIdx.z, layer = z / 2, which = z % 2;
  __shared__ float tbuf[32][33];
  const float* src; unsigned short* dst; int Kd, Nd, n0, k0;
  if (which == 0) { src = Wf1 + (size_t)layer * DF; dst = Wf1T + (size_t)layer * DF;
                    Kd = DMODEL; Nd = FFDIM; n0 = blockIdx.x * 32; k0 = blockIdx.y * 32; }
  else            { src = Wf2 + (size_t)layer * DF; dst = Wf2T + (size_t)layer * DF;
                    Kd = FFDIM; Nd = DMODEL; n0 = blockIdx.y * 32; k0 = blockIdx.x * 32; }
  const int tx = threadIdx.x, ty = threadIdx.y;
  #pragma unroll
  for (int r = ty; r < 32; r += 8)
    tbuf[r][tx] = src[(size_t)(k0 + r) * Nd + n0 + tx];
  __syncthreads();
  #pragma unroll
  for (int r = ty; r < 32; r += 8)
    dst[(size_t)(n0 + r) * Kd + k0 + tx] = f2b(tbuf[tx][r]);
}

// ================= bf16 MFMA GEMM (BMx128 tile, BK=64, swizzled LDS, XCD swizzle) ======
template <int BM>
__global__ __launch_bounds__(256) void gemm_mfma_kernel(
    const unsigned short* __restrict__ A, const unsigned short* __restrict__ Bt,
    const float* __restrict__ bias, float* __restrict__ Cf,
    unsigned short* __restrict__ Cb, int N, int K, int act)
{
  constexpr int ASLOTS = BM * 8;           // 16B slots in A tile (BM x 64 bf16)
  constexpr int MI = BM / 32;              // A-frags per wave
  __shared__ unsigned short As[ASLOTS * 8];
  __shared__ unsigned short Bs[8192];      // 128 x 64 bf16
  const int tid = threadIdx.x, wave = tid >> 6, lane = tid & 63;
  // XCD-aware bijective swizzle (all grids have nwg % 8 == 0)
  const int gx = gridDim.x, nwg = gx * gridDim.y;
  int flat = blockIdx.y * gx + blockIdx.x;
  flat = (flat & 7) * (nwg >> 3) + (flat >> 3);
  const int bm = (flat % gx) * BM, bn = (flat / gx) * 128;
  const int wr = (wave >> 1) * (BM / 2), wc = (wave & 1) * 64;
  f32x4 acc[MI][4];
  const f32x4 zz = {0.f, 0.f, 0.f, 0.f};
  #pragma unroll
  for (int i = 0; i < MI; ++i)
    #pragma unroll
    for (int j = 0; j < 4; ++j) acc[i][j] = zz;

  for (int k0 = 0; k0 < K; k0 += 64) {
    #pragma unroll
    for (int it = 0; it < ASLOTS / 256; ++it) {
      const int s = it * 256 + tid;
      const int mr = s >> 3;
      const int kg = (s & 7) ^ (mr & 7);
      const unsigned short* src = A + (size_t)(bm + mr) * K + k0 + kg * 8;
      __builtin_amdgcn_global_load_lds(
          (const __attribute__((address_space(1))) void*)src,
          (__attribute__((address_space(3))) void*)&As[(size_t)(it * 256 + wave * 64) * 8], 16, 0, 0);
    }
    #pragma unroll
    for (int it = 0; it < 4; ++it) {
      const int s = it * 256 + tid;
      const int mr = s >> 3;
      const int kg = (s & 7) ^ (mr & 7);
      const unsigned short* src = Bt + (size_t)(bn + mr) * K + k0 + kg * 8;
      __builtin_amdgcn_global_load_lds(
          (const __attribute__((address_space(1))) void*)src,
          (__attribute__((address_space(3))) void*)&Bs[(size_t)(it * 256 + wave * 64) * 8], 16, 0, 0);
    }
    __syncthreads();
    #pragma unroll
    for (int ks = 0; ks < 2; ++ks) {
      const int kg = ks * 4 + (lane >> 4);
      short8 af[MI], bfr[4];
      #pragma unroll
      for (int i = 0; i < MI; ++i) {
        const int m = wr + i * 16 + (lane & 15);
        af[i] = *(const short8*)&As[(m * 8 + (kg ^ (m & 7))) * 8];
      }
      #pragma unroll
      for (int j = 0; j < 4; ++j) {
        const int n = wc + j * 16 + (lane & 15);
        bfr[j] = *(const short8*)&Bs[(n * 8 + (kg ^ (n & 7))) * 8];
      }
      #pragma unroll
      for (int i = 0; i < MI; ++i)
        #pragma unroll
        for (int j = 0; j < 4; ++j)
          acc[i][j] = __builtin_amdgcn_mfma_f32_16x16x32_bf16(af[i], bfr[j], acc[i][j], 0, 0, 0);
    }
    __syncthreads();
  }

  const int lr = (lane >> 4) * 4, lc = lane & 15;
  #pragma unroll
  for (int i = 0; i < MI; ++i) {
    #pragma unroll
    for (int j = 0; j < 4; ++j) {
      const int n = bn + wc + j * 16 + lc;
      const float bv = bias[n];
      #pragma unroll
      for (int p = 0; p < 4; ++p) {
        const int m = bm + wr + i * 16 + lr + p;
        float val = acc[i][j][p] + bv;
        if (act) val = gelu_f(val);
        if (Cf) Cf[(size_t)m * N + n] = val;
        if (Cb) Cb[(size_t)m * N + n] = f2b(val);
      }
    }
  }
}

// ================= banded sliding-window attention, MFMA flash (bf16 inputs) =========
__global__ __launch_bounds__(256) void banded_attn_mfma_kernel(
    const unsigned short* __restrict__ qkvb, const int* __restrict__ am,
    unsigned short* __restrict__ outb)
{
  const int h = blockIdx.x, nc = blockIdx.y;
  const int tid = threadIdx.x, wave = tid >> 6, lane = tid & 63;
  const int c = lane & 15, g = lane >> 4;

  __shared__ unsigned short Ks[8192];   // K tile, slot-swizzled (16 KB)
  __shared__ unsigned short Vt[8192];   // V^T tile [dim][key], slot-swizzled (16 KB)
  __shared__ unsigned short Ps[16384];  // P tile [qrow][key], slot-swizzled (32 KB)
  __shared__ float smcls[128];
  __shared__ float sv0[64];
  __shared__ int   sam[128];

  // ---- CLS score (f32 accumulation over bf16) + V0 staging ----
  if (tid < 64) sv0[tid] = b2f(qkvb[2 * DMODEL + h * DHEAD + tid]);
  if (tid < 128) {
    const int qrow = nc * CHUNK + tid;
    const unsigned short* qp = qkvb + (size_t)qrow * QKV_N + h * DHEAD;
    const unsigned short* k0 = qkvb + DMODEL + h * DHEAD;
    float d = 0.f;
    #pragma unroll
    for (int dd = 0; dd < 64; dd += 8) {
      const short8 a8 = *(const short8*)(qp + dd);
      const short8 b8 = *(const short8*)(k0 + dd);
      #pragma unroll
      for (int e = 0; e < 8; ++e)
        d += b2f((unsigned short)a8[e]) * b2f((unsigned short)b8[e]);
    }
    smcls[tid] = (am[0] > 0) ? d * 0.125f : -1e9f;
  }

  // ---- Q fragments in registers ----
  short8 af[2][2];
  #pragma unroll
  for (int i = 0; i < 2; ++i)
    #pragma unroll
    for (int ks = 0; ks < 2; ++ks) {
      const int qrow = nc * CHUNK + wave * 32 + i * 16 + c;
      af[i][ks] = *(const short8*)(qkvb + (size_t)qrow * QKV_N + h * DHEAD + (ks * 4 + g) * 8);
    }

  __syncthreads();

  float mrow[2][4], lrow[2][4];
  f32x4 acc_o[2][4];
  #pragma unroll
  for (int i = 0; i < 2; ++i)
    #pragma unroll
    for (int p = 0; p < 4; ++p) {
      mrow[i][p] = smcls[wave * 32 + i * 16 + g * 4 + p];
      lrow[i][p] = 1.f;
    }
  #pragma unroll
  for (int i = 0; i < 2; ++i)
    #pragma unroll
    for (int j = 0; j < 4; ++j) {
      const float v0 = sv0[j * 16 + c];
      acc_o[i][j][0] = v0; acc_o[i][j][1] = v0; acc_o[i][j][2] = v0; acc_o[i][j][3] = v0;
    }

  for (int kci = 0; kci < 3; ++kci) {
    const int ck = nc - 1 + kci;
    if (ck < 0 || ck > 15) continue;   // out-of-range chunk: reference contribution is exp->0
    __syncthreads();                   // previous tile fully consumed

    // ---- stage K tile via global_load_lds (swizzled slots) ----
    #pragma unroll
    for (int it = 0; it < 4; ++it) {
      const int sidx = it * 256 + tid;
      const int mr = sidx >> 3;
      const int kg = (sidx & 7) ^ (mr & 7);
      const unsigned short* src = qkvb + (size_t)(ck * CHUNK + mr) * QKV_N + DMODEL + h * DHEAD + kg * 8;
      __builtin_amdgcn_global_load_lds(
          (const __attribute__((address_space(1))) void*)src,
          (__attribute__((address_space(3))) void*)&Ks[(size_t)(it * 256 + wave * 64) * 8], 16, 0, 0);
    }
    // ---- stage V^T tile (reg-staged, pair-packed b32 writes) ----
    {
      const int kp = tid & 63, dh = tid >> 6;
      const unsigned short* v0p = qkvb + (size_t)(ck * CHUNK + 2 * kp) * QKV_N + 2 * DMODEL + h * DHEAD + dh * 16;
      const short8 a0 = *(const short8*)(v0p);
      const short8 a1 = *(const short8*)(v0p + 8);
      const short8 b0 = *(const short8*)(v0p + QKV_N);
      const short8 b1 = *(const short8*)(v0p + QKV_N + 8);
      #pragma unroll
      for (int dd = 0; dd < 16; ++dd) {
        const int dim = dh * 16 + dd;
        const unsigned short lo = (unsigned short)(dd < 8 ? a0[dd] : a1[dd - 8]);
        const unsigned short hi = (unsigned short)(dd < 8 ? b0[dd] : b1[dd - 8]);
        const unsigned int w = (unsigned int)lo | ((unsigned int)hi << 16);
        const int si = dim * 128 + (((kp >> 2) ^ (dim & 7)) << 3) + ((kp & 3) << 1);
        *(unsigned int*)&Vt[si] = w;
      }
    }
    if (tid < 128) sam[tid] = am[ck * CHUNK + tid];
    __syncthreads();

    // ---- S = Q @ K^T ----
    f32x4 accs[2][8];
    const f32x4 zz = {0.f, 0.f, 0.f, 0.f};
    #pragma unroll
    for (int i = 0; i < 2; ++i)
      #pragma unroll
      for (int j = 0; j < 8; ++j) accs[i][j] = zz;
    #pragma unroll
    for (int ks = 0; ks < 2; ++ks) {
      const int kg = ks * 4 + g;
      short8 bfr[8];
      #pragma unroll
      for (int j = 0; j < 8; ++j) {
        const int jj = j * 16 + c;
        bfr[j] = *(const short8*)&Ks[(jj * 8 + (kg ^ (jj & 7))) * 8];
      }
      #pragma unroll
      for (int i = 0; i < 2; ++i)
        #pragma unroll
        for (int j = 0; j < 8; ++j)
          accs[i][j] = __builtin_amdgcn_mfma_f32_16x16x32_bf16(af[i][ks], bfr[j], accs[i][j], 0, 0, 0);
    }

    // ---- mask + online softmax + P write ----
    #pragma unroll
    for (int i = 0; i < 2; ++i) {
      #pragma unroll
      for (int p = 0; p < 4; ++p) {
        const int mloc = wave * 32 + i * 16 + g * 4 + p;
        const int qi = nc * CHUNK + mloc;
        float sv[8];
        float rmax = -1e30f;
        #pragma unroll
        for (int j = 0; j < 8; ++j) {
          const int jj = j * 16 + c;
          const int kj = ck * CHUNK + jj;
          const int diff = qi - kj;
          const bool ok = (diff <= 128) && (diff >= -128) && (kj != 0) && (sam[jj] > 0);
          const float s = ok ? accs[i][j][p] * 0.125f : -1e9f;
          sv[j] = s;
          rmax = fmaxf(rmax, s);
        }
        rmax = fmaxf(rmax, __shfl_xor(rmax, 1));
        rmax = fmaxf(rmax, __shfl_xor(rmax, 2));
        rmax = fmaxf(rmax, __shfl_xor(rmax, 4));
        rmax = fmaxf(rmax, __shfl_xor(rmax, 8));
        const float mnew = fmaxf(mrow[i][p], rmax);
        const float corr = __expf(mrow[i][p] - mnew);
        float psum = 0.f;
        #pragma unroll
        for (int j = 0; j < 8; ++j) {
          const float pv = __expf(sv[j] - mnew);
          sv[j] = pv;
          psum += pv;
        }
        psum += __shfl_xor(psum, 1);
        psum += __shfl_xor(psum, 2);
        psum += __shfl_xor(psum, 4);
        psum += __shfl_xor(psum, 8);
        lrow[i][p] = lrow[i][p] * corr + psum;
        mrow[i][p] = mnew;
        #pragma unroll
        for (int j = 0; j < 4; ++j) acc_o[i][j][p] *= corr;
        #pragma unroll
        for (int j = 0; j < 8; ++j) {
          const int key = j * 16 + c;
          const int kslot = key >> 3;
          Ps[mloc * 128 + ((kslot ^ (mloc & 7)) << 3) + (key & 7)] = f2b(sv[j]);
        }
      }
    }
    // wave-private P rows: drain LDS writes before cross-lane reads (no block barrier needed)
    asm volatile("s_waitcnt lgkmcnt(0)" ::: "memory");

    // ---- O += P @ V ----
    #pragma unroll
    for (int ks2 = 0; ks2 < 4; ++ks2) {
      const int kg2 = ks2 * 4 + g;
      short8 pa[2], vb[4];
      #pragma unroll
      for (int i = 0; i < 2; ++i) {
        const int row = wave * 32 + i * 16 + c;
        pa[i] = *(const short8*)&Ps[row * 128 + ((kg2 ^ (row & 7)) << 3)];
      }
      #pragma unroll
      for (int j = 0; j < 4; ++j) {
        const int n = j * 16 + c;
        vb[j] = *(const short8*)&Vt[n * 128 + ((kg2 ^ (n & 7)) << 3)];
      }
      #pragma unroll
      for (int i = 0; i < 2; ++i)
        #pragma unroll
        for (int j = 0; j < 4; ++j)
          acc_o[i][j] = __builtin_amdgcn_mfma_f32_16x16x32_bf16(pa[i], vb[j], acc_o[i][j], 0, 0, 0);
    }
  }

  // ---- finalize ----
  #pragma unroll
  for (int i = 0; i < 2; ++i) {
    #pragma unroll
    for (int p = 0; p < 4; ++p) {
      const float rl = (lrow[i][p] > 0.f) ? 1.f / lrow[i][p] : 0.f;
      const int row = nc * CHUNK + wave * 32 + i * 16 + g * 4 + p;
      #pragma unroll
      for (int j = 0; j < 4; ++j)
        outb[(size_t)row * DMODEL + h * DHEAD + j * 16 + c] = f2b(acc_o[i][j][p] * rl);
    }
  }
}

// ================= global CLS row attention: partials + combine (bf16 K/V) ===========
__global__ __launch_bounds__(256) void glb_attn_partial_kernel(
    const float* __restrict__ qg0, const unsigned short* __restrict__ qkvb,
    const int* __restrict__ am, float* __restrict__ part)
{
  const int h = blockIdx.x, g = blockIdx.y, t = threadIdx.x;
  const unsigned short* kg = qkvb + 3 * DMODEL;
  const unsigned short* vg = qkvb + 4 * DMODEL;
  __shared__ float sc[256];
  __shared__ float qs[64];
  __shared__ float red[4];
  __shared__ float pb[4][64];
  if (t < 64) qs[t] = qg0[h * DHEAD + t] * 0.125f;
  __syncthreads();
  const int s0 = g * 256 + t;
  float d = 0.f;
  const unsigned short* kr = kg + (size_t)s0 * QKV_N + h * DHEAD;
  #pragma unroll
  for (int d0 = 0; d0 < DHEAD; d0 += 8) {
    const short8 k8 = *(const short8*)(kr + d0);
    #pragma unroll
    for (int e = 0; e < 8; ++e)
      d += qs[d0 + e] * b2f((unsigned short)k8[e]);
  }
  const float mysc = (am[s0] > 0) ? d : -1e9f;
  float mx = mysc;
  #pragma unroll
  for (int off = 32; off; off >>= 1) mx = fmaxf(mx, __shfl_down(mx, off));
  if ((t & 63) == 0) red[t >> 6] = mx;
  __syncthreads();
  mx = fmaxf(fmaxf(red[0], red[1]), fmaxf(red[2], red[3]));
  __syncthreads();
  const float e = expf(mysc - mx);
  sc[t] = e;
  float sum = e;
  #pragma unroll
  for (int off = 32; off; off >>= 1) sum += __shfl_down(sum, off);
  if ((t & 63) == 0) red[t >> 6] = sum;
  __syncthreads();
  const float lsum = red[0] + red[1] + red[2] + red[3];
  const int dd = t & 63, grp = t >> 6;
  float pa = 0.f;
  for (int i = 0; i < 64; ++i) {
    const int li = grp * 64 + i;
    pa = fmaf(sc[li], b2f(vg[(size_t)(g * 256 + li) * QKV_N + h * DHEAD + dd]), pa);
  }
  pb[grp][dd] = pa;
  __syncthreads();
  float* pr = part + (size_t)(h * 8 + g) * 66;
  if (t < 64) pr[2 + t] = pb[0][t] + pb[1][t] + pb[2][t] + pb[3][t];
  if (t == 0) { pr[0] = mx; pr[1] = lsum; }
}

__global__ __launch_bounds__(64) void glb_attn_combine_kernel(
    const float* __restrict__ part, unsigned short* __restrict__ outb)
{
  const int h = blockIdx.x, d = threadIdx.x;
  float M = -1e30f;
  for (int g = 0; g < 8; ++g) M = fmaxf(M, part[(size_t)(h * 8 + g) * 66]);
  float L = 0.f, o = 0.f;
  for (int g = 0; g < 8; ++g) {
    const float* pr = part + (size_t)(h * 8 + g) * 66;
    const float cc = (pr[0] > -1e8f) ? expf(pr[0] - M) : 0.f;
    L += pr[1] * cc;
    o += pr[2 + d] * cc;
  }
  outb[h * DHEAD + d] = f2b(o / L);
}

// ================= split-k GEMV =================
__global__ __launch_bounds__(256) void gemv_partial_kernel(
    const float* __restrict__ xrow, const float* __restrict__ W, float* __restrict__ part)
{
  const int b = blockIdx.x, t = threadIdx.x;
  float s0 = 0.f, s1 = 0.f, s2 = 0.f;
  for (int kk = 0; kk < 48; ++kk) {
    const int k = b * 48 + kk;
    const float xv = xrow[k];
    const float* wr = W + (size_t)k * DMODEL;
    s0 = fmaf(xv, wr[t], s0);
    s1 = fmaf(xv, wr[t + 256], s1);
    s2 = fmaf(xv, wr[t + 512], s2);
  }
  part[b * DMODEL + t] = s0;
  part[b * DMODEL + t + 256] = s1;
  part[b * DMODEL + t + 512] = s2;
}

__global__ __launch_bounds__(256) void gemv_reduce_kernel(
    const float* __restrict__ part, const float* __restrict__ bias,
    float* __restrict__ y, int act)
{
  const int n = blockIdx.x * 256 + threadIdx.x;
  float s = bias[n];
  #pragma unroll
  for (int b = 0; b < 16; ++b) s += part[b * DMODEL + n];
  if (act) s = gelu_f(s);
  y[n] = s;
}

// ================= final head =================
__global__ __launch_bounds__(256) void head_final_kernel(
    const float* __restrict__ h2, const float* __restrict__ Wout,
    const float* __restrict__ bout, float* __restrict__ out)
{
  const int tid = threadIdx.x;
  __shared__ float red[4];
  float p = h2[tid]*Wout[tid] + h2[tid+256]*Wout[tid+256] + h2[tid+512]*Wout[tid+512];
  #pragma unroll
  for (int off = 32; off; off >>= 1) p += __shfl_down(p, off);
  if ((tid & 63) == 0) red[tid >> 6] = p;
  __syncthreads();
  if (tid == 0) {
    const float logit = red[0] + red[1] + red[2] + red[3] + bout[0];
    const float sig = 1.0f / (1.0f + expf(-logit));
    const unsigned int bits = __float_as_uint(sig);
    const unsigned int bf = (bits + 0x7FFFu + ((bits >> 16) & 1u)) >> 16;
    out[0] = __uint_as_float((bits & 0xFFFF0000u) | (bf & 0xFFFFu));
  }
}

extern "C" void kernel_launch(void* const* d_in, const int* in_sizes, int n_in,
                              void* d_out, int out_size, void* d_ws, size_t ws_size,
                              hipStream_t stream)
{
  const int*   ids  = (const int*)d_in[0];
  const int*   am   = (const int*)d_in[1];
  const float* wemb = (const float*)d_in[2];
  const float* pemb = (const float*)d_in[3];
  const float* emb_g = (const float*)d_in[4];
  const float* emb_b = (const float*)d_in[5];
  const float* Wq  = (const float*)d_in[6];
  const float* bq  = (const float*)d_in[7];
  const float* Wk  = (const float*)d_in[8];
  const float* bk  = (const float*)d_in[9];
  const float* Wv  = (const float*)d_in[10];
  const float* bv  = (const float*)d_in[11];
  const float* Wqg = (const float*)d_in[12];
  const float* bqg = (const float*)d_in[13];
  const float* Wkg = (const float*)d_in[14];
  const float* bkg = (const float*)d_in[15];
  const float* Wvg = (const float*)d_in[16];
  const float* bvg = (const float*)d_in[17];
  const float* Wo  = (const float*)d_in[18];
  const float* bo  = (const float*)d_in[19];
  const float* ln1g = (const float*)d_in[20];
  const float* ln1b = (const float*)d_in[21];
  const float* Wf1 = (const float*)d_in[22];
  const float* bf1 = (const float*)d_in[23];
  const float* Wf2 = (const float*)d_in[24];
  const float* bf2 = (const float*)d_in[25];
  const float* ln2g = (const float*)d_in[26];
  const float* ln2b = (const float*)d_in[27];
  const float* hng = (const float*)d_in[28];
  const float* hnb = (const float*)d_in[29];
  const float* W1  = (const float*)d_in[30];
  const float* b1  = (const float*)d_in[31];
  const float* W2  = (const float*)d_in[32];
  const float* b2  = (const float*)d_in[33];
  const float* Wout = (const float*)d_in[34];
  const float* bout = (const float*)d_in[35];

  char* wp = (char*)d_ws;
  auto alloc = [&](size_t bytes) -> void* {
    void* r = (void*)wp;
    wp += (bytes + 255) & ~(size_t)255;
    return r;
  };
  float*          x         = (float*)alloc((size_t)S_LEN * DMODEL * 4);
  unsigned short* xb        = (unsigned short*)alloc((size_t)S_LEN * DMODEL * 2);
  unsigned short* qkvb      = (unsigned short*)alloc((size_t)S_LEN * QKV_N * 2);
  unsigned short* attnb     = (unsigned short*)alloc((size_t)S_LEN * DMODEL * 2);
  unsigned short* tmpb      = (unsigned short*)alloc((size_t)S_LEN * FFDIM * 2);
  float*          tmpf      = (float*)alloc((size_t)S_LEN * DMODEL * 4);
  unsigned short* WqkvT_all = (unsigned short*)alloc((size_t)NLAYER * 5 * DD * 2);
  unsigned short* WoT_all   = (unsigned short*)alloc((size_t)NLAYER * DD * 2);
  unsigned short* Wf1T_all  = (unsigned short*)alloc((size_t)NLAYER * DF * 2);
  unsigned short* Wf2T_all  = (unsigned short*)alloc((size_t)NLAYER * DF * 2);
  float*          bqkv_all  = (float*)alloc((size_t)NLAYER * QKV_N * 4);
  float*          qg0       = (float*)alloc((size_t)DMODEL * 4);
  float*          gpart     = (float*)alloc((size_t)16 * DMODEL * 4);
  float*          glbp      = (float*)alloc((size_t)NHEAD * 8 * 66 * 4);
  float*          hb        = (float*)alloc((size_t)3 * DMODEL * 4);

  const dim3 blk32x8(32, 8);
  // one-shot weight conversion for all layers (BW-bound, 2 launches)
  conv_all_dd_kernel<<<dim3(24, 24, 6 * NLAYER), blk32x8, 0, stream>>>(
      Wq, Wk, Wv, Wkg, Wvg, Wo, bq, bk, bv, bkg, bvg, WqkvT_all, WoT_all, bqkv_all);
  conv_all_ffn_kernel<<<dim3(96, 24, 2 * NLAYER), blk32x8, 0, stream>>>(
      Wf1, Wf2, Wf1T_all, Wf2T_all);

  embed_ln_kernel<<<S_LEN, 256, 0, stream>>>(ids, wemb, pemb, emb_g, emb_b, x, xb);

  for (int l = 0; l < NLAYER; ++l) {
    const size_t wdd = (size_t)l * DD;
    const size_t vd  = (size_t)l * DMODEL;
    const size_t vf  = (size_t)l * FFDIM;
    const unsigned short* WqkvT = WqkvT_all + (size_t)l * 5 * DD;
    const unsigned short* WoT   = WoT_all + wdd;
    const unsigned short* Wf1T  = Wf1T_all + (size_t)l * DF;
    const unsigned short* Wf2T  = Wf2T_all + (size_t)l * DF;
    const float* bqkv = bqkv_all + (size_t)l * QKV_N;

    // fused q|k|v|kg|vg projection: [2048,768] @ [768,3840] -> bf16 only
    gemm_mfma_kernel<128><<<dim3(16, 30), 256, 0, stream>>>(
        xb, WqkvT, bqkv, (float*)nullptr, qkvb, QKV_N, DMODEL, 0);

    gemv_partial_kernel<<<16, 256, 0, stream>>>(x, Wqg + wdd, gpart);
    gemv_reduce_kernel<<<3, 256, 0, stream>>>(gpart, bqg + vd, qg0, 0);

    banded_attn_mfma_kernel<<<dim3(NHEAD, NCHUNK), 256, 0, stream>>>(qkvb, am, attnb);
    glb_attn_partial_kernel<<<dim3(NHEAD, 8), 256, 0, stream>>>(qg0, qkvb, am, glbp);
    glb_attn_combine_kernel<<<NHEAD, 64, 0, stream>>>(glbp, attnb);

    gemm_mfma_kernel<64><<<dim3(32, 6), 256, 0, stream>>>(
        attnb, WoT, bo + vd, tmpf, (unsigned short*)nullptr, DMODEL, DMODEL, 0);
    add_ln_kernel<<<S_LEN, 256, 0, stream>>>(x, tmpf, ln1g + vd, ln1b + vd, xb);

    gemm_mfma_kernel<128><<<dim3(16, 24), 256, 0, stream>>>(
        xb, Wf1T, bf1 + vf, (float*)nullptr, tmpb, FFDIM, DMODEL, 1);
    gemm_mfma_kernel<64><<<dim3(32, 6), 256, 0, stream>>>(
        tmpb, Wf2T, bf2 + vd, tmpf, (unsigned short*)nullptr, DMODEL, FFDIM, 0);
    add_ln_kernel<<<S_LEN, 256, 0, stream>>>(x, tmpf, ln2g + vd, ln2b + vd, xb);
  }

  ln_vec_kernel<<<1, 256, 0, stream>>>(x, hng, hnb, hb);
  gemv_partial_kernel<<<16, 256, 0, stream>>>(hb, W1, gpart);
  gemv_reduce_kernel<<<3, 256, 0, stream>>>(gpart, b1, hb + DMODEL, 1);
  gemv_partial_kernel<<<16, 256, 0, stream>>>(hb + DMODEL, W2, gpart);
  gemv_reduce_kernel<<<3, 256, 0, stream>>>(gpart, b2, hb + 2 * DMODEL, 1);
  head_final_kernel<<<1, 256, 0, stream>>>(hb + 2 * DMODEL, Wout, bout, (float*)d_out);
}